// Round 1
// baseline (2314.902 us; speedup 1.0000x reference)
//
#include <hip/hip_runtime.h>

#define NN 100000
#define C 128
#define VEC 16

// ---------------------------------------------------------------------------
// Sparse 27-tap conv: out[i] = sum_k x[nbr[k,i]] @ W[k]   (skip invalid taps)
// 128 threads (thread = output channel c), 32-point tile, LDS out-tile.
// ---------------------------------------------------------------------------
__global__ __launch_bounds__(128) void conv1_sparse(const float* __restrict__ x,
                                                    const int* __restrict__ nbr,
                                                    const float* __restrict__ W,
                                                    float* __restrict__ out) {
    const int c = threadIdx.x;
    const int base = blockIdx.x * 32;
    __shared__ float outt[32][C];
    __shared__ int sj[32];
    __shared__ unsigned long long smask;
#pragma unroll
    for (int p = 0; p < 32; ++p) outt[p][c] = 0.f;

    for (int k = 0; k < 27; ++k) {
        __syncthreads();                       // protect sj from prior-iter readers
        if (c < 32) sj[c] = nbr[k * NN + base + c];
        __syncthreads();
        if (c < 64) {
            int jj = (c < 32) ? sj[c] : -1;    // guard: no OOB shared read
            unsigned long long mk = __ballot(jj >= 0);
            if (c == 0) smask = mk;
        }
        __syncthreads();
        unsigned long long mask = smask;
        if (!mask) continue;                   // uniform: whole tap empty
        const float* Wk = W + (size_t)k * C * C;
        for (int cin0 = 0; cin0 < C; cin0 += 4) {
            float w0 = Wk[(cin0 + 0) * C + c];
            float w1 = Wk[(cin0 + 1) * C + c];
            float w2 = Wk[(cin0 + 2) * C + c];
            float w3 = Wk[(cin0 + 3) * C + c];
            unsigned long long m = mask;
            while (m) {
                int p = __builtin_ctzll(m); m &= (m - 1);
                int j = sj[p];
                float4 xv = *reinterpret_cast<const float4*>(x + (size_t)j * C + cin0);
                outt[p][c] += xv.x * w0 + xv.y * w1 + xv.z * w2 + xv.w * w3;
            }
        }
    }
    __syncthreads();
#pragma unroll
    for (int p = 0; p < 32; ++p) out[(size_t)(base + p) * C + c] = outt[p][c];
}

// ---------------------------------------------------------------------------
// Dense [N,128] @ [128,128] matmul. thread = out channel, 32-point tile,
// register accumulators, wave-uniform broadcast float4 input reads.
// ---------------------------------------------------------------------------
__global__ __launch_bounds__(128) void mm128(const float* __restrict__ in,
                                             const float* __restrict__ W,
                                             float* __restrict__ out) {
    const int c = threadIdx.x;
    const size_t base = (size_t)blockIdx.x * 32;
    float acc[32];
#pragma unroll
    for (int p = 0; p < 32; ++p) acc[p] = 0.f;
    for (int cin0 = 0; cin0 < C; cin0 += 4) {
        float w0 = W[(cin0 + 0) * C + c];
        float w1 = W[(cin0 + 1) * C + c];
        float w2 = W[(cin0 + 2) * C + c];
        float w3 = W[(cin0 + 3) * C + c];
#pragma unroll
        for (int p = 0; p < 32; ++p) {
            float4 xv = *reinterpret_cast<const float4*>(in + (base + p) * C + cin0);
            acc[p] += xv.x * w0 + xv.y * w1 + xv.z * w2 + xv.w * w3;
        }
    }
#pragma unroll
    for (int p = 0; p < 32; ++p) out[(base + p) * C + c] = acc[p];
}

// ---------------------------------------------------------------------------
// q = x @ q_w  ([N,128] @ [128,16])
// ---------------------------------------------------------------------------
__global__ __launch_bounds__(256) void qmm(const float* __restrict__ x,
                                           const float* __restrict__ qw,
                                           float* __restrict__ outq) {
    const int v = threadIdx.x & 15, p = threadIdx.x >> 4;
    const size_t i = (size_t)blockIdx.x * 16 + p;
    float acc = 0.f;
    for (int cin0 = 0; cin0 < C; cin0 += 4) {
        float4 xv = *reinterpret_cast<const float4*>(x + i * C + cin0);
        acc += xv.x * qw[(cin0 + 0) * VEC + v] + xv.y * qw[(cin0 + 1) * VEC + v]
             + xv.z * qw[(cin0 + 2) * VEC + v] + xv.w * qw[(cin0 + 3) * VEC + v];
    }
    outq[i * VEC + v] = acc;
}

// ---------------------------------------------------------------------------
// BN statistics: two-stage deterministic reduction.
// ---------------------------------------------------------------------------
__global__ __launch_bounds__(256) void stats_partial128(const float* __restrict__ buf,
                                                        float* __restrict__ ps,
                                                        float* __restrict__ pq) {
    const int ch = threadIdx.x & 127, half = threadIdx.x >> 7;
    float s = 0.f, q = 0.f;
    for (int i = blockIdx.x * 2 + half; i < NN; i += gridDim.x * 2) {
        float val = buf[(size_t)i * C + ch];
        s += val; q += val * val;
    }
    __shared__ float ls[256], lq[256];
    ls[threadIdx.x] = s; lq[threadIdx.x] = q;
    __syncthreads();
    if (threadIdx.x < 128) {
        ps[blockIdx.x * C + ch] = ls[threadIdx.x] + ls[threadIdx.x + 128];
        pq[blockIdx.x * C + ch] = lq[threadIdx.x] + lq[threadIdx.x + 128];
    }
}

__global__ __launch_bounds__(256) void stats_partial16(const float* __restrict__ buf,
                                                       float* __restrict__ ps,
                                                       float* __restrict__ pq) {
    const int ch = threadIdx.x & 15, grp = threadIdx.x >> 4;
    float s = 0.f, q = 0.f;
    for (int i = blockIdx.x * 16 + grp; i < NN; i += gridDim.x * 16) {
        float val = buf[(size_t)i * VEC + ch];
        s += val; q += val * val;
    }
    __shared__ float ls[256], lq[256];
    ls[threadIdx.x] = s; lq[threadIdx.x] = q;
    __syncthreads();
    if (threadIdx.x < 16) {
        float ss = 0.f, qq = 0.f;
        for (int g2 = 0; g2 < 16; ++g2) { ss += ls[g2 * 16 + ch]; qq += lq[g2 * 16 + ch]; }
        ps[blockIdx.x * VEC + ch] = ss; pq[blockIdx.x * VEC + ch] = qq;
    }
}

__global__ void stats_final(const float* __restrict__ ps, const float* __restrict__ pq,
                            int nb, int cdim,
                            const float* __restrict__ g, const float* __restrict__ b,
                            float* __restrict__ a, float* __restrict__ cc) {
    int ch = threadIdx.x;
    if (ch >= cdim) return;
    float s = 0.f, q = 0.f;
    for (int i = 0; i < nb; ++i) { s += ps[i * cdim + ch]; q += pq[i * cdim + ch]; }
    float m = s / (float)NN;
    float var = q / (float)NN - m * m;
    var = fmaxf(var, 0.f);
    float rs = rsqrtf(var + 1e-5f);
    float av = g[ch] * rs;
    a[ch] = av;
    cc[ch] = b[ch] - m * av;
}

// in-place y = relu(y*a[ch] + c[ch]); mask = C-1 (power of two)
__global__ __launch_bounds__(256) void bn_relu_ip(float* __restrict__ buf,
                                                  const float* __restrict__ a,
                                                  const float* __restrict__ cc,
                                                  int total4, int mask) {
    for (int t = blockIdx.x * blockDim.x + threadIdx.x; t < total4; t += gridDim.x * blockDim.x) {
        float4 v = reinterpret_cast<float4*>(buf)[t];
        int ch = (t * 4) & mask;
        v.x = fmaxf(fmaf(v.x, a[ch + 0], cc[ch + 0]), 0.f);
        v.y = fmaxf(fmaf(v.y, a[ch + 1], cc[ch + 1]), 0.f);
        v.z = fmaxf(fmaf(v.z, a[ch + 2], cc[ch + 2]), 0.f);
        v.w = fmaxf(fmaf(v.w, a[ch + 3], cc[ch + 3]), 0.f);
        reinterpret_cast<float4*>(buf)[t] = v;
    }
}

// ---------------------------------------------------------------------------
// Fused: pairwise scores (3 experts) -> softmax -> channelwise convs -> mix.
// One block per point. Lanes 0..15: scores+softmax; all 128 lanes: mix.
// ---------------------------------------------------------------------------
__global__ __launch_bounds__(128) void attn_fused(const float* __restrict__ vbuf,
                                                  const float* __restrict__ qbuf,
                                                  const int* __restrict__ nA,
                                                  const int* __restrict__ nB,
                                                  const int* __restrict__ nC,
                                                  const float* __restrict__ cb0,
                                                  const float* __restrict__ cb1,
                                                  const float* __restrict__ cb2,
                                                  float* __restrict__ outm) {
    const int i = blockIdx.x;
    const int tid = threadIdx.x;
    __shared__ float attn[VEC][3];
    if (tid < VEC) {
        float qi = qbuf[(size_t)i * VEC + tid];
        float sc0, sc1, sc2;
        {
            float acc = 0.f; int cnt = 0;
            for (int k = 0; k < 7; ++k) {
                int j = nA[k * NN + i];
                if (j >= 0) { acc += qbuf[(size_t)j * VEC + tid]; ++cnt; }
            }
            sc0 = qi * acc / (float)(cnt > 0 ? cnt : 1);
        }
        {
            float acc = 0.f; int cnt = 0;
            for (int k = 0; k < 27; ++k) {
                int j = nB[k * NN + i];
                if (j >= 0) { acc += qbuf[(size_t)j * VEC + tid]; ++cnt; }
            }
            sc1 = qi * acc / (float)(cnt > 0 ? cnt : 1);
        }
        {
            float acc = 0.f; int cnt = 0;
            for (int k = 0; k < 7; ++k) {
                int j = nC[k * NN + i];
                if (j >= 0) { acc += qbuf[(size_t)j * VEC + tid]; ++cnt; }
            }
            sc2 = qi * acc / (float)(cnt > 0 ? cnt : 1);
        }
        float mx = fmaxf(sc0, fmaxf(sc1, sc2));
        float e0 = expf(sc0 - mx), e1 = expf(sc1 - mx), e2 = expf(sc2 - mx);
        float inv = 1.f / (e0 + e1 + e2);
        attn[tid][0] = e0 * inv; attn[tid][1] = e1 * inv; attn[tid][2] = e2 * inv;
    }
    __syncthreads();
    const int c = tid;
    float a0 = attn[c >> 3][0], a1 = attn[c >> 3][1], a2 = attn[c >> 3][2];
    float ov = 0.f;
    {
        float s = 0.f;
        for (int k = 0; k < 7; ++k) {
            int j = nA[k * NN + i];
            if (j >= 0) s += cb0[k * C + c] * vbuf[(size_t)j * C + c];
        }
        ov += a0 * s;
    }
    {
        float s = 0.f;
        for (int k = 0; k < 27; ++k) {
            int j = nB[k * NN + i];
            if (j >= 0) s += cb1[k * C + c] * vbuf[(size_t)j * C + c];
        }
        ov += a1 * s;
    }
    {
        float s = 0.f;
        for (int k = 0; k < 7; ++k) {
            int j = nC[k * NN + i];
            if (j >= 0) s += cb2[k * C + c] * vbuf[(size_t)j * C + c];
        }
        ov += a2 * s;
    }
    outm[(size_t)i * C + c] = ov;
}

// out = relu(buf*a + c) + x
__global__ __launch_bounds__(256) void final_bn_res(const float* __restrict__ buf,
                                                    const float* __restrict__ a,
                                                    const float* __restrict__ cc,
                                                    const float* __restrict__ x,
                                                    float* __restrict__ out, int total4) {
    for (int t = blockIdx.x * blockDim.x + threadIdx.x; t < total4; t += gridDim.x * blockDim.x) {
        float4 v = reinterpret_cast<const float4*>(buf)[t];
        float4 xv = reinterpret_cast<const float4*>(x)[t];
        int ch = (t * 4) & 127;
        v.x = fmaxf(fmaf(v.x, a[ch + 0], cc[ch + 0]), 0.f) + xv.x;
        v.y = fmaxf(fmaf(v.y, a[ch + 1], cc[ch + 1]), 0.f) + xv.y;
        v.z = fmaxf(fmaf(v.z, a[ch + 2], cc[ch + 2]), 0.f) + xv.z;
        v.w = fmaxf(fmaf(v.w, a[ch + 3], cc[ch + 3]), 0.f) + xv.w;
        reinterpret_cast<float4*>(out)[t] = v;
    }
}

extern "C" void kernel_launch(void* const* d_in, const int* in_sizes, int n_in,
                              void* d_out, int out_size, void* d_ws, size_t ws_size,
                              hipStream_t stream) {
    (void)in_sizes; (void)n_in; (void)out_size; (void)ws_size;
    const float* x    = (const float*)d_in[0];
    const float* v1_w = (const float*)d_in[1];
    const float* v1_g = (const float*)d_in[2];
    const float* v1_b = (const float*)d_in[3];
    const float* v2_w = (const float*)d_in[4];
    const float* v2_g = (const float*)d_in[5];
    const float* v2_b = (const float*)d_in[6];
    const float* q_w  = (const float*)d_in[7];
    const float* q_g  = (const float*)d_in[8];
    const float* q_b  = (const float*)d_in[9];
    const float* cb0  = (const float*)d_in[10];
    const float* cb1  = (const float*)d_in[11];
    const float* cb2  = (const float*)d_in[12];
    const float* out_w = (const float*)d_in[13];
    const float* out_g = (const float*)d_in[14];
    const float* out_b = (const float*)d_in[15];
    const int* nbrA = (const int*)d_in[16];   // cross2, K=7
    const int* nbrB = (const int*)d_in[17];   // cube,  K=27
    const int* nbrC = (const int*)d_in[18];   // cross3, K=7
    float* out = (float*)d_out;

    float* w = (float*)d_ws;
    size_t o = 0;
    float* bufA = w + o; o += (size_t)NN * C;
    float* bufB = w + o; o += (size_t)NN * C;
    float* bufQ = w + o; o += (size_t)NN * VEC;
    float* ps   = w + o; o += 256 * C;
    float* pq   = w + o; o += 256 * C;
    float* ps16 = w + o; o += 128 * VEC;
    float* pq16 = w + o; o += 128 * VEC;
    float* a1 = w + o; o += C;  float* c1 = w + o; o += C;
    float* a2 = w + o; o += C;  float* c2 = w + o; o += C;
    float* ao = w + o; o += C;  float* co = w + o; o += C;
    float* aq = w + o; o += VEC; float* cq = w + o; o += VEC;

    const int total4  = NN * C / 4;    // 3,200,000
    const int total4q = NN * VEC / 4;  // 400,000

    // value branch conv1 (cube-27) -> BN -> relu
    conv1_sparse<<<NN / 32, 128, 0, stream>>>(x, nbrB, v1_w, bufA);
    stats_partial128<<<256, 256, 0, stream>>>(bufA, ps, pq);
    stats_final<<<1, 128, 0, stream>>>(ps, pq, 256, C, v1_g, v1_b, a1, c1);
    bn_relu_ip<<<2048, 256, 0, stream>>>(bufA, a1, c1, total4, 127);

    // 1x1 conv -> BN -> relu  => v in bufB
    mm128<<<NN / 32, 128, 0, stream>>>(bufA, v2_w, bufB);
    stats_partial128<<<256, 256, 0, stream>>>(bufB, ps, pq);
    stats_final<<<1, 128, 0, stream>>>(ps, pq, 256, C, v2_g, v2_b, a2, c2);
    bn_relu_ip<<<2048, 256, 0, stream>>>(bufB, a2, c2, total4, 127);

    // query branch => q in bufQ
    qmm<<<NN / 16, 256, 0, stream>>>(x, q_w, bufQ);
    stats_partial16<<<128, 256, 0, stream>>>(bufQ, ps16, pq16);
    stats_final<<<1, 64, 0, stream>>>(ps16, pq16, 128, VEC, q_g, q_b, aq, cq);
    bn_relu_ip<<<1024, 256, 0, stream>>>(bufQ, aq, cq, total4q, 15);

    // fused expert convs + attention mix => bufA
    attn_fused<<<NN, 128, 0, stream>>>(bufB, bufQ, nbrA, nbrB, nbrC, cb0, cb1, cb2, bufA);

    // output 1x1 conv -> BN -> relu -> +x
    mm128<<<NN / 32, 128, 0, stream>>>(bufA, out_w, bufB);
    stats_partial128<<<256, 256, 0, stream>>>(bufB, ps, pq);
    stats_final<<<1, 128, 0, stream>>>(ps, pq, 256, C, out_g, out_b, ao, co);
    final_bn_res<<<2048, 256, 0, stream>>>(bufB, ao, co, x, out, total4);
}

// Round 2
// 1478.172 us; speedup vs baseline: 1.5661x; 1.5661x over previous
//
#include <hip/hip_runtime.h>

#define NN 100000
#define C 128
#define VEC 16

typedef __bf16 bfx8 __attribute__((ext_vector_type(8)));
typedef float f32x4 __attribute__((ext_vector_type(4)));

__device__ inline unsigned pack_bf2(float a, float b) {
    unsigned ua = __float_as_uint(a);
    unsigned ub = __float_as_uint(b);
    ua = (ua + 0x7fffu + ((ua >> 16) & 1u)) >> 16;
    ub = (ub + 0x7fffu + ((ub >> 16) & 1u)) >> 16;
    return ua | (ub << 16);
}

// ---------------------------------------------------------------------------
// Pre-swizzle W [27][128][128] fp32 -> bf16 in exact MFMA B-fragment order:
// Wf[(((kt*4+ks)*8+nt)*64+l)*8+e] = bf16(W[kt][ks*32+(l>>4)*8+e][nt*16+(l&15)])
// ---------------------------------------------------------------------------
__global__ __launch_bounds__(256) void wconv_bf16(const float* __restrict__ W,
                                                  unsigned short* __restrict__ Wf) {
    int F = blockIdx.x * 256 + threadIdx.x;   // grid sized exactly 27*16384
    int e = F & 7, l = (F >> 3) & 63, nt = (F >> 9) & 7, ks = (F >> 12) & 3, kt = F >> 14;
    int cin = ks * 32 + (l >> 4) * 8 + e;
    int cout = nt * 16 + (l & 15);
    float v = W[((size_t)kt * C + cin) * C + cout];
    unsigned u = __float_as_uint(v);
    Wf[F] = (unsigned short)((u + 0x7fffu + ((u >> 16) & 1u)) >> 16);
}

// ---------------------------------------------------------------------------
// Sparse 27-tap conv via per-tap gather-MFMA.
// Block: 256 threads (4 waves), tile = 64 output points.
// Per tap: wave0 compacts valid (p,j) pairs; stage <=16 gathered bf16 x-rows
// into LDS; 4 waves each do 2 col-tiles x 4 k-steps of mfma 16x16x32;
// scatter C-frags into padded LDS out-tile. No atomics, deterministic.
// ---------------------------------------------------------------------------
#define AROW 136   // padded row stride (ushorts) for Ash
#define OROW 132   // padded row stride (floats) for outt

__global__ __launch_bounds__(256) void conv1_mfma(const float* __restrict__ x,
                                                  const int* __restrict__ nbr,
                                                  const bfx8* __restrict__ Wf,
                                                  float* __restrict__ out) {
    const int tid = threadIdx.x;
    const int l = tid & 63;
    const int w = tid >> 6;
    const int base = blockIdx.x * 64;

    __shared__ float outt[64 * OROW];
    __shared__ unsigned short Ash[16 * AROW];
    __shared__ int sjs[64], sps[64];
    __shared__ int sn;

    for (int idx = tid; idx < 64 * OROW; idx += 256) outt[idx] = 0.f;
    for (int idx = tid; idx < 16 * AROW; idx += 256) Ash[idx] = 0;

    const bool pok = (base + tid) < NN;       // only meaningful for tid<64
    int jcur = -1;
    if (tid < 64 && pok) jcur = nbr[base + tid];

    for (int kt = 0; kt < 27; ++kt) {
        __syncthreads();   // protect Ash/lists from previous tap's readers
        if (tid < 64) {
            int j = jcur;
            int jn = -1;
            if (kt < 26 && pok) jn = nbr[(size_t)(kt + 1) * NN + base + tid];
            unsigned long long mask = __ballot(j >= 0);
            if (j >= 0) {
                int pos = __popcll(mask & ((1ull << tid) - 1ull));
                sjs[pos] = j;
                sps[pos] = tid;
            }
            if (tid == 0) sn = (int)__popcll(mask);
            jcur = jn;
        }
        __syncthreads();
        const int n = sn;
        const int nchunks = (n + 15) >> 4;

        for (int ch = 0; ch < nchunks; ++ch) {
            if (ch) __syncthreads();
            // stage chunk rows into Ash (bf16)
            {
                int m = tid >> 4, g = tid & 15;
                int pidx = ch * 16 + m;
                if (pidx < n) {
                    int j = sjs[pidx];
                    const float* xr = x + (size_t)j * C + g * 8;
                    float4 xa = *reinterpret_cast<const float4*>(xr);
                    float4 xb = *reinterpret_cast<const float4*>(xr + 4);
                    uint4 pk;
                    pk.x = pack_bf2(xa.x, xa.y);
                    pk.y = pack_bf2(xa.z, xa.w);
                    pk.z = pack_bf2(xb.x, xb.y);
                    pk.w = pack_bf2(xb.z, xb.w);
                    *reinterpret_cast<uint4*>(&Ash[m * AROW + g * 8]) = pk;
                }
            }
            __syncthreads();
            // MFMA: wave w covers output cols [32w, 32w+32)
            f32x4 acc0 = {0.f, 0.f, 0.f, 0.f};
            f32x4 acc1 = {0.f, 0.f, 0.f, 0.f};
            const unsigned short* arow = &Ash[(l & 15) * AROW + (l >> 4) * 8];
#pragma unroll
            for (int ks = 0; ks < 4; ++ks) {
                bfx8 af = *reinterpret_cast<const bfx8*>(arow + ks * 32);
                bfx8 b0 = Wf[((kt * 4 + ks) * 8 + 2 * w) * 64 + l];
                bfx8 b1 = Wf[((kt * 4 + ks) * 8 + 2 * w + 1) * 64 + l];
                acc0 = __builtin_amdgcn_mfma_f32_16x16x32_bf16(af, b0, acc0, 0, 0, 0);
                acc1 = __builtin_amdgcn_mfma_f32_16x16x32_bf16(af, b1, acc1, 0, 0, 0);
            }
            // scatter C-frags: col = l&15, row = (l>>4)*4 + r
#pragma unroll
            for (int r = 0; r < 4; ++r) {
                int row = (l >> 4) * 4 + r;
                int pidx = ch * 16 + row;
                if (pidx < n) {
                    int p = sps[pidx];
                    outt[p * OROW + w * 32 + (l & 15)] += acc0[r];
                    outt[p * OROW + w * 32 + 16 + (l & 15)] += acc1[r];
                }
            }
        }
    }
    __syncthreads();
    for (int idx = tid; idx < 64 * C; idx += 256) {
        int p = idx >> 7, c = idx & 127;
        if (base + p < NN) out[(size_t)(base + p) * C + c] = outt[p * OROW + c];
    }
}

// ---------------------------------------------------------------------------
// Dense [N,128] @ [128,128] matmul. thread = out channel, 32-point tile.
// ---------------------------------------------------------------------------
__global__ __launch_bounds__(128) void mm128(const float* __restrict__ in,
                                             const float* __restrict__ W,
                                             float* __restrict__ out) {
    const int c = threadIdx.x;
    const size_t base = (size_t)blockIdx.x * 32;
    float acc[32];
#pragma unroll
    for (int p = 0; p < 32; ++p) acc[p] = 0.f;
    for (int cin0 = 0; cin0 < C; cin0 += 4) {
        float w0 = W[(cin0 + 0) * C + c];
        float w1 = W[(cin0 + 1) * C + c];
        float w2 = W[(cin0 + 2) * C + c];
        float w3 = W[(cin0 + 3) * C + c];
#pragma unroll
        for (int p = 0; p < 32; ++p) {
            float4 xv = *reinterpret_cast<const float4*>(in + (base + p) * C + cin0);
            acc[p] += xv.x * w0 + xv.y * w1 + xv.z * w2 + xv.w * w3;
        }
    }
#pragma unroll
    for (int p = 0; p < 32; ++p) out[(base + p) * C + c] = acc[p];
}

// ---------------------------------------------------------------------------
// q = x @ q_w  ([N,128] @ [128,16])
// ---------------------------------------------------------------------------
__global__ __launch_bounds__(256) void qmm(const float* __restrict__ x,
                                           const float* __restrict__ qw,
                                           float* __restrict__ outq) {
    const int v = threadIdx.x & 15, p = threadIdx.x >> 4;
    const size_t i = (size_t)blockIdx.x * 16 + p;
    float acc = 0.f;
    for (int cin0 = 0; cin0 < C; cin0 += 4) {
        float4 xv = *reinterpret_cast<const float4*>(x + i * C + cin0);
        acc += xv.x * qw[(cin0 + 0) * VEC + v] + xv.y * qw[(cin0 + 1) * VEC + v]
             + xv.z * qw[(cin0 + 2) * VEC + v] + xv.w * qw[(cin0 + 3) * VEC + v];
    }
    outq[i * VEC + v] = acc;
}

// ---------------------------------------------------------------------------
// BN statistics: two-stage deterministic reduction.
// ---------------------------------------------------------------------------
__global__ __launch_bounds__(256) void stats_partial128(const float* __restrict__ buf,
                                                        float* __restrict__ ps,
                                                        float* __restrict__ pq) {
    const int ch = threadIdx.x & 127, half = threadIdx.x >> 7;
    float s = 0.f, q = 0.f;
    for (int i = blockIdx.x * 2 + half; i < NN; i += gridDim.x * 2) {
        float val = buf[(size_t)i * C + ch];
        s += val; q += val * val;
    }
    __shared__ float ls[256], lq[256];
    ls[threadIdx.x] = s; lq[threadIdx.x] = q;
    __syncthreads();
    if (threadIdx.x < 128) {
        ps[blockIdx.x * C + ch] = ls[threadIdx.x] + ls[threadIdx.x + 128];
        pq[blockIdx.x * C + ch] = lq[threadIdx.x] + lq[threadIdx.x + 128];
    }
}

__global__ __launch_bounds__(256) void stats_partial16(const float* __restrict__ buf,
                                                       float* __restrict__ ps,
                                                       float* __restrict__ pq) {
    const int ch = threadIdx.x & 15, grp = threadIdx.x >> 4;
    float s = 0.f, q = 0.f;
    for (int i = blockIdx.x * 16 + grp; i < NN; i += gridDim.x * 16) {
        float val = buf[(size_t)i * VEC + ch];
        s += val; q += val * val;
    }
    __shared__ float ls[256], lq[256];
    ls[threadIdx.x] = s; lq[threadIdx.x] = q;
    __syncthreads();
    if (threadIdx.x < 16) {
        float ss = 0.f, qq = 0.f;
        for (int g2 = 0; g2 < 16; ++g2) { ss += ls[g2 * 16 + ch]; qq += lq[g2 * 16 + ch]; }
        ps[blockIdx.x * VEC + ch] = ss; pq[blockIdx.x * VEC + ch] = qq;
    }
}

__global__ void stats_final(const float* __restrict__ ps, const float* __restrict__ pq,
                            int nb, int cdim,
                            const float* __restrict__ g, const float* __restrict__ b,
                            float* __restrict__ a, float* __restrict__ cc) {
    int ch = threadIdx.x;
    if (ch >= cdim) return;
    float s = 0.f, q = 0.f;
    for (int i = 0; i < nb; ++i) { s += ps[i * cdim + ch]; q += pq[i * cdim + ch]; }
    float m = s / (float)NN;
    float var = q / (float)NN - m * m;
    var = fmaxf(var, 0.f);
    float rs = rsqrtf(var + 1e-5f);
    float av = g[ch] * rs;
    a[ch] = av;
    cc[ch] = b[ch] - m * av;
}

// in-place y = relu(y*a[ch] + c[ch]); mask = C-1 (power of two)
__global__ __launch_bounds__(256) void bn_relu_ip(float* __restrict__ buf,
                                                  const float* __restrict__ a,
                                                  const float* __restrict__ cc,
                                                  int total4, int mask) {
    for (int t = blockIdx.x * blockDim.x + threadIdx.x; t < total4; t += gridDim.x * blockDim.x) {
        float4 v = reinterpret_cast<float4*>(buf)[t];
        int ch = (t * 4) & mask;
        v.x = fmaxf(fmaf(v.x, a[ch + 0], cc[ch + 0]), 0.f);
        v.y = fmaxf(fmaf(v.y, a[ch + 1], cc[ch + 1]), 0.f);
        v.z = fmaxf(fmaf(v.z, a[ch + 2], cc[ch + 2]), 0.f);
        v.w = fmaxf(fmaf(v.w, a[ch + 3], cc[ch + 3]), 0.f);
        reinterpret_cast<float4*>(buf)[t] = v;
    }
}

// ---------------------------------------------------------------------------
// Fused: pairwise scores (3 experts) -> softmax -> channelwise convs -> mix.
// ---------------------------------------------------------------------------
__global__ __launch_bounds__(128) void attn_fused(const float* __restrict__ vbuf,
                                                  const float* __restrict__ qbuf,
                                                  const int* __restrict__ nA,
                                                  const int* __restrict__ nB,
                                                  const int* __restrict__ nC,
                                                  const float* __restrict__ cb0,
                                                  const float* __restrict__ cb1,
                                                  const float* __restrict__ cb2,
                                                  float* __restrict__ outm) {
    const int i = blockIdx.x;
    const int tid = threadIdx.x;
    __shared__ float attn[VEC][3];
    if (tid < VEC) {
        float qi = qbuf[(size_t)i * VEC + tid];
        float sc0, sc1, sc2;
        {
            float acc = 0.f; int cnt = 0;
            for (int k = 0; k < 7; ++k) {
                int j = nA[k * NN + i];
                if (j >= 0) { acc += qbuf[(size_t)j * VEC + tid]; ++cnt; }
            }
            sc0 = qi * acc / (float)(cnt > 0 ? cnt : 1);
        }
        {
            float acc = 0.f; int cnt = 0;
            for (int k = 0; k < 27; ++k) {
                int j = nB[k * NN + i];
                if (j >= 0) { acc += qbuf[(size_t)j * VEC + tid]; ++cnt; }
            }
            sc1 = qi * acc / (float)(cnt > 0 ? cnt : 1);
        }
        {
            float acc = 0.f; int cnt = 0;
            for (int k = 0; k < 7; ++k) {
                int j = nC[k * NN + i];
                if (j >= 0) { acc += qbuf[(size_t)j * VEC + tid]; ++cnt; }
            }
            sc2 = qi * acc / (float)(cnt > 0 ? cnt : 1);
        }
        float mx = fmaxf(sc0, fmaxf(sc1, sc2));
        float e0 = expf(sc0 - mx), e1 = expf(sc1 - mx), e2 = expf(sc2 - mx);
        float inv = 1.f / (e0 + e1 + e2);
        attn[tid][0] = e0 * inv; attn[tid][1] = e1 * inv; attn[tid][2] = e2 * inv;
    }
    __syncthreads();
    const int c = tid;
    float a0 = attn[c >> 3][0], a1 = attn[c >> 3][1], a2 = attn[c >> 3][2];
    float ov = 0.f;
    {
        float s = 0.f;
        for (int k = 0; k < 7; ++k) {
            int j = nA[k * NN + i];
            if (j >= 0) s += cb0[k * C + c] * vbuf[(size_t)j * C + c];
        }
        ov += a0 * s;
    }
    {
        float s = 0.f;
        for (int k = 0; k < 27; ++k) {
            int j = nB[k * NN + i];
            if (j >= 0) s += cb1[k * C + c] * vbuf[(size_t)j * C + c];
        }
        ov += a1 * s;
    }
    {
        float s = 0.f;
        for (int k = 0; k < 7; ++k) {
            int j = nC[k * NN + i];
            if (j >= 0) s += cb2[k * C + c] * vbuf[(size_t)j * C + c];
        }
        ov += a2 * s;
    }
    outm[(size_t)i * C + c] = ov;
}

// out = relu(buf*a + c) + x
__global__ __launch_bounds__(256) void final_bn_res(const float* __restrict__ buf,
                                                    const float* __restrict__ a,
                                                    const float* __restrict__ cc,
                                                    const float* __restrict__ x,
                                                    float* __restrict__ out, int total4) {
    for (int t = blockIdx.x * blockDim.x + threadIdx.x; t < total4; t += gridDim.x * blockDim.x) {
        float4 v = reinterpret_cast<const float4*>(buf)[t];
        float4 xv = reinterpret_cast<const float4*>(x)[t];
        int ch = (t * 4) & 127;
        v.x = fmaxf(fmaf(v.x, a[ch + 0], cc[ch + 0]), 0.f) + xv.x;
        v.y = fmaxf(fmaf(v.y, a[ch + 1], cc[ch + 1]), 0.f) + xv.y;
        v.z = fmaxf(fmaf(v.z, a[ch + 2], cc[ch + 2]), 0.f) + xv.z;
        v.w = fmaxf(fmaf(v.w, a[ch + 3], cc[ch + 3]), 0.f) + xv.w;
        reinterpret_cast<float4*>(out)[t] = v;
    }
}

extern "C" void kernel_launch(void* const* d_in, const int* in_sizes, int n_in,
                              void* d_out, int out_size, void* d_ws, size_t ws_size,
                              hipStream_t stream) {
    (void)in_sizes; (void)n_in; (void)out_size; (void)ws_size;
    const float* x    = (const float*)d_in[0];
    const float* v1_w = (const float*)d_in[1];
    const float* v1_g = (const float*)d_in[2];
    const float* v1_b = (const float*)d_in[3];
    const float* v2_w = (const float*)d_in[4];
    const float* v2_g = (const float*)d_in[5];
    const float* v2_b = (const float*)d_in[6];
    const float* q_w  = (const float*)d_in[7];
    const float* q_g  = (const float*)d_in[8];
    const float* q_b  = (const float*)d_in[9];
    const float* cb0  = (const float*)d_in[10];
    const float* cb1  = (const float*)d_in[11];
    const float* cb2  = (const float*)d_in[12];
    const float* out_w = (const float*)d_in[13];
    const float* out_g = (const float*)d_in[14];
    const float* out_b = (const float*)d_in[15];
    const int* nbrA = (const int*)d_in[16];   // cross2, K=7
    const int* nbrB = (const int*)d_in[17];   // cube,  K=27
    const int* nbrC = (const int*)d_in[18];   // cross3, K=7
    float* out = (float*)d_out;

    float* w = (float*)d_ws;
    size_t o = 0;
    float* bufA = w + o; o += (size_t)NN * C;
    float* bufB = w + o; o += (size_t)NN * C;
    float* bufQ = w + o; o += (size_t)NN * VEC;
    float* ps   = w + o; o += 256 * C;
    float* pq   = w + o; o += 256 * C;
    float* ps16 = w + o; o += 128 * VEC;
    float* pq16 = w + o; o += 128 * VEC;
    float* a1 = w + o; o += C;  float* c1 = w + o; o += C;
    float* a2 = w + o; o += C;  float* c2 = w + o; o += C;
    float* ao = w + o; o += C;  float* co = w + o; o += C;
    float* aq = w + o; o += VEC; float* cq = w + o; o += VEC;
    unsigned short* wfrag = (unsigned short*)(w + o); o += (27 * 16384 * 2) / 4;

    const int total4  = NN * C / 4;    // 3,200,000
    const int total4q = NN * VEC / 4;  // 400,000

    // pre-swizzle v1_w into MFMA B-fragment order (bf16)
    wconv_bf16<<<27 * 16384 / 256, 256, 0, stream>>>(v1_w, wfrag);

    // value branch conv1 (cube-27) -> BN -> relu
    conv1_mfma<<<(NN + 63) / 64, 256, 0, stream>>>(x, nbrB, (const bfx8*)wfrag, bufA);
    stats_partial128<<<256, 256, 0, stream>>>(bufA, ps, pq);
    stats_final<<<1, 128, 0, stream>>>(ps, pq, 256, C, v1_g, v1_b, a1, c1);
    bn_relu_ip<<<2048, 256, 0, stream>>>(bufA, a1, c1, total4, 127);

    // 1x1 conv -> BN -> relu  => v in bufB
    mm128<<<NN / 32, 128, 0, stream>>>(bufA, v2_w, bufB);
    stats_partial128<<<256, 256, 0, stream>>>(bufB, ps, pq);
    stats_final<<<1, 128, 0, stream>>>(ps, pq, 256, C, v2_g, v2_b, a2, c2);
    bn_relu_ip<<<2048, 256, 0, stream>>>(bufB, a2, c2, total4, 127);

    // query branch => q in bufQ
    qmm<<<NN / 16, 256, 0, stream>>>(x, q_w, bufQ);
    stats_partial16<<<128, 256, 0, stream>>>(bufQ, ps16, pq16);
    stats_final<<<1, 64, 0, stream>>>(ps16, pq16, 128, VEC, q_g, q_b, aq, cq);
    bn_relu_ip<<<1024, 256, 0, stream>>>(bufQ, aq, cq, total4q, 15);

    // fused expert convs + attention mix => bufA
    attn_fused<<<NN, 128, 0, stream>>>(bufB, bufQ, nbrA, nbrB, nbrC, cb0, cb1, cb2, bufA);

    // output 1x1 conv -> BN -> relu -> +x
    mm128<<<NN / 32, 128, 0, stream>>>(bufA, out_w, bufB);
    stats_partial128<<<256, 256, 0, stream>>>(bufB, ps, pq);
    stats_final<<<1, 128, 0, stream>>>(ps, pq, 256, C, out_g, out_b, ao, co);
    final_bn_res<<<2048, 256, 0, stream>>>(bufB, ao, co, x, out, total4);
}

// Round 3
// 852.236 us; speedup vs baseline: 2.7163x; 1.7345x over previous
//
#include <hip/hip_runtime.h>

#define NN 100000
#define C 128
#define VEC 16
#define AROW 136   // padded LDS row stride (ushorts): 272B rows -> 2-way-max bank alias (free)

typedef __bf16 bfx8 __attribute__((ext_vector_type(8)));
typedef float f32x4 __attribute__((ext_vector_type(4)));

__device__ inline unsigned pack_bf2(float a, float b) {
    unsigned ua = __float_as_uint(a);
    unsigned ub = __float_as_uint(b);
    ua = (ua + 0x7fffu + ((ua >> 16) & 1u)) >> 16;
    ub = (ub + 0x7fffu + ((ub >> 16) & 1u)) >> 16;
    return ua | (ub << 16);
}

// ---------------------------------------------------------------------------
// Pre-swizzle W [KT][128][128] fp32 -> bf16 in exact MFMA B-fragment order:
// Wf[(((kt*4+ks)*8+nt)*64+l)*8+e] = bf16(W[kt][ks*32+(l>>4)*8+e][nt*16+(l&15)])
// Works for KT=27 (grid 1728) and KT=1 (grid 64).
// ---------------------------------------------------------------------------
__global__ __launch_bounds__(256) void wconv_bf16(const float* __restrict__ W,
                                                  unsigned short* __restrict__ Wf) {
    int F = blockIdx.x * 256 + threadIdx.x;
    int e = F & 7, l = (F >> 3) & 63, nt = (F >> 9) & 7, ks = (F >> 12) & 3, kt = F >> 14;
    int cin = ks * 32 + (l >> 4) * 8 + e;
    int cout = nt * 16 + (l & 15);
    float v = W[((size_t)kt * C + cin) * C + cout];
    unsigned u = __float_as_uint(v);
    Wf[F] = (unsigned short)((u + 0x7fffu + ((u >> 16) & 1u)) >> 16);
}

// ---------------------------------------------------------------------------
// Sparse 27-tap conv, 16-point tile, accumulators in registers across taps.
// Per tap: ballot over 16 points; skip all-invalid taps (uniform); stage
// valid rows (bf16) / zeros; 4 waves x (2 col-tiles x 4 ks) MFMA.
// ---------------------------------------------------------------------------
__global__ __launch_bounds__(256) void conv1_mfma16(const float* __restrict__ x,
                                                    const int* __restrict__ nbr,
                                                    const bfx8* __restrict__ Wf,
                                                    float* __restrict__ out) {
    const int tid = threadIdx.x, l = tid & 63, w = tid >> 6;
    const int base = blockIdx.x * 16;     // grid exact: 6250*16 = 100000
    __shared__ unsigned short Ash[16 * AROW];
    __shared__ float outt[16 * 132];
    __shared__ int sj[16];
    __shared__ int ssm;

    f32x4 acc0 = {0.f, 0.f, 0.f, 0.f};
    f32x4 acc1 = {0.f, 0.f, 0.f, 0.f};
    int jreg = (tid < 16) ? nbr[base + tid] : -1;

    for (int kt = 0; kt < 27; ++kt) {
        __syncthreads();                    // Ash/sj safe to overwrite
        if (tid < 16) {
            int j = jreg;
            jreg = (kt < 26) ? nbr[(size_t)(kt + 1) * NN + base + tid] : -1;
            unsigned long long mk = __ballot(j >= 0);
            sj[tid] = j;
            if (tid == 0) ssm = (int)mk;
        }
        __syncthreads();
        int m = ssm;
        if (!m) continue;                   // uniform skip: whole tap empty
        {
            int r = tid >> 4, g = tid & 15;
            uint4 pk = {0u, 0u, 0u, 0u};
            int j = sj[r];
            if (j >= 0) {
                const float* xr = x + (size_t)j * C + g * 8;
                float4 xa = *reinterpret_cast<const float4*>(xr);
                float4 xb = *reinterpret_cast<const float4*>(xr + 4);
                pk.x = pack_bf2(xa.x, xa.y); pk.y = pack_bf2(xa.z, xa.w);
                pk.z = pack_bf2(xb.x, xb.y); pk.w = pack_bf2(xb.z, xb.w);
            }
            *reinterpret_cast<uint4*>(&Ash[r * AROW + g * 8]) = pk;
        }
        __syncthreads();
        const unsigned short* arow = &Ash[(l & 15) * AROW + (l >> 4) * 8];
#pragma unroll
        for (int ks = 0; ks < 4; ++ks) {
            bfx8 af = *reinterpret_cast<const bfx8*>(arow + ks * 32);
            bfx8 b0 = Wf[((kt * 4 + ks) * 8 + 2 * w) * 64 + l];
            bfx8 b1 = Wf[((kt * 4 + ks) * 8 + 2 * w + 1) * 64 + l];
            acc0 = __builtin_amdgcn_mfma_f32_16x16x32_bf16(af, b0, acc0, 0, 0, 0);
            acc1 = __builtin_amdgcn_mfma_f32_16x16x32_bf16(af, b1, acc1, 0, 0, 0);
        }
    }
    __syncthreads();
#pragma unroll
    for (int r = 0; r < 4; ++r) {
        int row = (l >> 4) * 4 + r;
        outt[row * 132 + w * 32 + (l & 15)] = acc0[r];
        outt[row * 132 + w * 32 + 16 + (l & 15)] = acc1[r];
    }
    __syncthreads();
    {
        int r = tid >> 4, g = tid & 15;
        float4 v0 = *reinterpret_cast<float4*>(&outt[r * 132 + g * 8]);
        float4 v1 = *reinterpret_cast<float4*>(&outt[r * 132 + g * 8 + 4]);
        float* op = out + (size_t)(base + r) * C + g * 8;
        *reinterpret_cast<float4*>(op) = v0;
        *reinterpret_cast<float4*>(op + 4) = v1;
    }
}

// ---------------------------------------------------------------------------
// Dense [N,128] @ [128,128] MFMA matmul with optional fused input BN+ReLU.
// ---------------------------------------------------------------------------
__global__ __launch_bounds__(256) void mm_bn_mfma(const float* __restrict__ in,
                                                  const float* __restrict__ a,
                                                  const float* __restrict__ cc,
                                                  int dorelu,
                                                  const bfx8* __restrict__ Wf,
                                                  float* __restrict__ out) {
    const int tid = threadIdx.x, l = tid & 63, w = tid >> 6;
    const size_t base = (size_t)blockIdx.x * 16;
    __shared__ unsigned short Ash[16 * AROW];
    __shared__ float outt[16 * 132];
    {
        int r = tid >> 4, g = tid & 15;
        const float* xr = in + (base + r) * C + g * 8;
        float4 xa = *reinterpret_cast<const float4*>(xr);
        float4 xb = *reinterpret_cast<const float4*>(xr + 4);
        if (dorelu) {
            float4 a4 = *reinterpret_cast<const float4*>(&a[g * 8]);
            float4 a4b = *reinterpret_cast<const float4*>(&a[g * 8 + 4]);
            float4 c4 = *reinterpret_cast<const float4*>(&cc[g * 8]);
            float4 c4b = *reinterpret_cast<const float4*>(&cc[g * 8 + 4]);
            xa.x = fmaxf(fmaf(xa.x, a4.x, c4.x), 0.f);
            xa.y = fmaxf(fmaf(xa.y, a4.y, c4.y), 0.f);
            xa.z = fmaxf(fmaf(xa.z, a4.z, c4.z), 0.f);
            xa.w = fmaxf(fmaf(xa.w, a4.w, c4.w), 0.f);
            xb.x = fmaxf(fmaf(xb.x, a4b.x, c4b.x), 0.f);
            xb.y = fmaxf(fmaf(xb.y, a4b.y, c4b.y), 0.f);
            xb.z = fmaxf(fmaf(xb.z, a4b.z, c4b.z), 0.f);
            xb.w = fmaxf(fmaf(xb.w, a4b.w, c4b.w), 0.f);
        }
        uint4 pk;
        pk.x = pack_bf2(xa.x, xa.y); pk.y = pack_bf2(xa.z, xa.w);
        pk.z = pack_bf2(xb.x, xb.y); pk.w = pack_bf2(xb.z, xb.w);
        *reinterpret_cast<uint4*>(&Ash[r * AROW + g * 8]) = pk;
    }
    __syncthreads();
    f32x4 acc0 = {0.f, 0.f, 0.f, 0.f};
    f32x4 acc1 = {0.f, 0.f, 0.f, 0.f};
    const unsigned short* arow = &Ash[(l & 15) * AROW + (l >> 4) * 8];
#pragma unroll
    for (int ks = 0; ks < 4; ++ks) {
        bfx8 af = *reinterpret_cast<const bfx8*>(arow + ks * 32);
        bfx8 b0 = Wf[(ks * 8 + 2 * w) * 64 + l];
        bfx8 b1 = Wf[(ks * 8 + 2 * w + 1) * 64 + l];
        acc0 = __builtin_amdgcn_mfma_f32_16x16x32_bf16(af, b0, acc0, 0, 0, 0);
        acc1 = __builtin_amdgcn_mfma_f32_16x16x32_bf16(af, b1, acc1, 0, 0, 0);
    }
#pragma unroll
    for (int r = 0; r < 4; ++r) {
        int row = (l >> 4) * 4 + r;
        outt[row * 132 + w * 32 + (l & 15)] = acc0[r];
        outt[row * 132 + w * 32 + 16 + (l & 15)] = acc1[r];
    }
    __syncthreads();
    {
        int r = tid >> 4, g = tid & 15;
        float4 v0 = *reinterpret_cast<float4*>(&outt[r * 132 + g * 8]);
        float4 v1 = *reinterpret_cast<float4*>(&outt[r * 132 + g * 8 + 4]);
        float* op = out + (base + r) * C + g * 8;
        *reinterpret_cast<float4*>(op) = v0;
        *reinterpret_cast<float4*>(op + 4) = v1;
    }
}

// ---------------------------------------------------------------------------
// q = x @ q_w  ([N,128] @ [128,16])
// ---------------------------------------------------------------------------
__global__ __launch_bounds__(256) void qmm(const float* __restrict__ x,
                                           const float* __restrict__ qw,
                                           float* __restrict__ outq) {
    const int v = threadIdx.x & 15, p = threadIdx.x >> 4;
    const size_t i = (size_t)blockIdx.x * 16 + p;
    float acc = 0.f;
    for (int cin0 = 0; cin0 < C; cin0 += 4) {
        float4 xv = *reinterpret_cast<const float4*>(x + i * C + cin0);
        acc += xv.x * qw[(cin0 + 0) * VEC + v] + xv.y * qw[(cin0 + 1) * VEC + v]
             + xv.z * qw[(cin0 + 2) * VEC + v] + xv.w * qw[(cin0 + 3) * VEC + v];
    }
    outq[i * VEC + v] = acc;
}

// ---------------------------------------------------------------------------
// BN statistics: two-stage deterministic reduction.
// ---------------------------------------------------------------------------
__global__ __launch_bounds__(256) void stats_partial128(const float* __restrict__ buf,
                                                        float* __restrict__ ps,
                                                        float* __restrict__ pq) {
    const int ch = threadIdx.x & 127, half = threadIdx.x >> 7;
    float s = 0.f, q = 0.f;
    for (int i = blockIdx.x * 2 + half; i < NN; i += gridDim.x * 2) {
        float val = buf[(size_t)i * C + ch];
        s += val; q += val * val;
    }
    __shared__ float ls[256], lq[256];
    ls[threadIdx.x] = s; lq[threadIdx.x] = q;
    __syncthreads();
    if (threadIdx.x < 128) {
        ps[blockIdx.x * C + ch] = ls[threadIdx.x] + ls[threadIdx.x + 128];
        pq[blockIdx.x * C + ch] = lq[threadIdx.x] + lq[threadIdx.x + 128];
    }
}

__global__ __launch_bounds__(256) void stats_partial16(const float* __restrict__ buf,
                                                       float* __restrict__ ps,
                                                       float* __restrict__ pq) {
    const int ch = threadIdx.x & 15, grp = threadIdx.x >> 4;
    float s = 0.f, q = 0.f;
    for (int i = blockIdx.x * 16 + grp; i < NN; i += gridDim.x * 16) {
        float val = buf[(size_t)i * VEC + ch];
        s += val; q += val * val;
    }
    __shared__ float ls[256], lq[256];
    ls[threadIdx.x] = s; lq[threadIdx.x] = q;
    __syncthreads();
    if (threadIdx.x < 16) {
        float ss = 0.f, qq = 0.f;
        for (int g2 = 0; g2 < 16; ++g2) { ss += ls[g2 * 16 + ch]; qq += lq[g2 * 16 + ch]; }
        ps[blockIdx.x * VEC + ch] = ss; pq[blockIdx.x * VEC + ch] = qq;
    }
}

__global__ void stats_final(const float* __restrict__ ps, const float* __restrict__ pq,
                            int nb, int cdim,
                            const float* __restrict__ g, const float* __restrict__ b,
                            float* __restrict__ a, float* __restrict__ cc) {
    int ch = threadIdx.x;
    if (ch >= cdim) return;
    float s = 0.f, q = 0.f;
    for (int i = 0; i < nb; ++i) { s += ps[i * cdim + ch]; q += pq[i * cdim + ch]; }
    float m = s / (float)NN;
    float var = q / (float)NN - m * m;
    var = fmaxf(var, 0.f);
    float rs = rsqrtf(var + 1e-5f);
    float av = g[ch] * rs;
    a[ch] = av;
    cc[ch] = b[ch] - m * av;
}

// in-place y = relu(y*a[ch] + c[ch]); mask = channel mask (power of two - 1)
__global__ __launch_bounds__(256) void bn_relu_ip(float* __restrict__ buf,
                                                  const float* __restrict__ a,
                                                  const float* __restrict__ cc,
                                                  int total4, int mask) {
    for (int t = blockIdx.x * blockDim.x + threadIdx.x; t < total4; t += gridDim.x * blockDim.x) {
        float4 v = reinterpret_cast<float4*>(buf)[t];
        int ch = (t * 4) & mask;
        v.x = fmaxf(fmaf(v.x, a[ch + 0], cc[ch + 0]), 0.f);
        v.y = fmaxf(fmaf(v.y, a[ch + 1], cc[ch + 1]), 0.f);
        v.z = fmaxf(fmaf(v.z, a[ch + 2], cc[ch + 2]), 0.f);
        v.w = fmaxf(fmaf(v.w, a[ch + 3], cc[ch + 3]), 0.f);
        reinterpret_cast<float4*>(buf)[t] = v;
    }
}

// BN+ReLU applied, output bf16 (v buffer for the attention stage)
__global__ __launch_bounds__(256) void bnrelu_bf16(const float* __restrict__ in,
                                                   const float* __restrict__ a,
                                                   const float* __restrict__ cc,
                                                   unsigned short* __restrict__ outh) {
    const int total8 = NN * C / 8;
    for (int t = blockIdx.x * 256 + threadIdx.x; t < total8; t += gridDim.x * 256) {
        int ch = (t * 8) & 127;
        const float* xr = in + (size_t)t * 8;
        float4 xa = *reinterpret_cast<const float4*>(xr);
        float4 xb = *reinterpret_cast<const float4*>(xr + 4);
        float4 a4 = *reinterpret_cast<const float4*>(&a[ch]);
        float4 a4b = *reinterpret_cast<const float4*>(&a[ch + 4]);
        float4 c4 = *reinterpret_cast<const float4*>(&cc[ch]);
        float4 c4b = *reinterpret_cast<const float4*>(&cc[ch + 4]);
        xa.x = fmaxf(fmaf(xa.x, a4.x, c4.x), 0.f);
        xa.y = fmaxf(fmaf(xa.y, a4.y, c4.y), 0.f);
        xa.z = fmaxf(fmaf(xa.z, a4.z, c4.z), 0.f);
        xa.w = fmaxf(fmaf(xa.w, a4.w, c4.w), 0.f);
        xb.x = fmaxf(fmaf(xb.x, a4b.x, c4b.x), 0.f);
        xb.y = fmaxf(fmaf(xb.y, a4b.y, c4b.y), 0.f);
        xb.z = fmaxf(fmaf(xb.z, a4b.z, c4b.z), 0.f);
        xb.w = fmaxf(fmaf(xb.w, a4b.w, c4b.w), 0.f);
        uint4 pk;
        pk.x = pack_bf2(xa.x, xa.y); pk.y = pack_bf2(xa.z, xa.w);
        pk.z = pack_bf2(xb.x, xb.y); pk.w = pack_bf2(xb.z, xb.w);
        *reinterpret_cast<uint4*>(&outh[(size_t)t * 8]) = pk;
    }
}

// ---------------------------------------------------------------------------
// Fused attention, 8 points per 256-thread block, ILP-batched gathers.
// Phase1: 328 indices -> LDS. Phase2: (p,v) threads compute scores+softmax.
// Phase3: (p, 4-ch group) threads do the channelwise mix from bf16 v.
// ---------------------------------------------------------------------------
__global__ __launch_bounds__(256) void attn_fused8(const unsigned short* __restrict__ vbf,
                                                   const float* __restrict__ qbuf,
                                                   const int* __restrict__ nA,
                                                   const int* __restrict__ nB,
                                                   const int* __restrict__ nC,
                                                   const float* __restrict__ cb0,
                                                   const float* __restrict__ cb1,
                                                   const float* __restrict__ cb2,
                                                   float* __restrict__ outm) {
    const int tid = threadIdx.x;
    const int base = blockIdx.x * 8;     // grid exact: 12500*8 = 100000
    __shared__ int sidx[8][48];
    __shared__ float sattn[8][16][4];

    for (int t = tid; t < 328; t += 256) {
        int p = t & 7, k = t >> 3;
        int i = base + p;
        int j;
        if (k < 7)       j = nA[(size_t)k * NN + i];
        else if (k < 34) j = nB[(size_t)(k - 7) * NN + i];
        else             j = nC[(size_t)(k - 34) * NN + i];
        sidx[p][k] = j;
    }
    __syncthreads();

    if (tid < 128) {
        int p = tid >> 4, v = tid & 15;
        size_t i = base + p;
        float qi = qbuf[i * VEC + v];
        float sc[3];
        {
            float acc = 0.f; int cnt = 0;
#pragma unroll
            for (int k = 0; k < 7; ++k) {
                int j = sidx[p][k]; int m = j >= 0; int jc = m ? j : 0;
                float val = qbuf[(size_t)jc * VEC + v];
                acc += m ? val : 0.f; cnt += m;
            }
            sc[0] = qi * acc / (float)(cnt > 0 ? cnt : 1);
        }
        {
            float acc = 0.f; int cnt = 0;
#pragma unroll 9
            for (int k = 0; k < 27; ++k) {
                int j = sidx[p][7 + k]; int m = j >= 0; int jc = m ? j : 0;
                float val = qbuf[(size_t)jc * VEC + v];
                acc += m ? val : 0.f; cnt += m;
            }
            sc[1] = qi * acc / (float)(cnt > 0 ? cnt : 1);
        }
        {
            float acc = 0.f; int cnt = 0;
#pragma unroll
            for (int k = 0; k < 7; ++k) {
                int j = sidx[p][34 + k]; int m = j >= 0; int jc = m ? j : 0;
                float val = qbuf[(size_t)jc * VEC + v];
                acc += m ? val : 0.f; cnt += m;
            }
            sc[2] = qi * acc / (float)(cnt > 0 ? cnt : 1);
        }
        float mx = fmaxf(sc[0], fmaxf(sc[1], sc[2]));
        float e0 = __expf(sc[0] - mx), e1 = __expf(sc[1] - mx), e2 = __expf(sc[2] - mx);
        float inv = 1.f / (e0 + e1 + e2);
        sattn[p][v][0] = e0 * inv; sattn[p][v][1] = e1 * inv; sattn[p][v][2] = e2 * inv;
    }
    __syncthreads();

    {
        int p = tid >> 5, cq = tid & 31, c0 = cq * 4;
        size_t i = base + p;
        float4 ac0 = {0.f, 0.f, 0.f, 0.f};
        float4 ac1 = {0.f, 0.f, 0.f, 0.f};
        float4 ac2 = {0.f, 0.f, 0.f, 0.f};
#pragma unroll
        for (int k = 0; k < 7; ++k) {
            int j = sidx[p][k]; float mf = (j >= 0) ? 1.f : 0.f; int jc = (j >= 0) ? j : 0;
            uint2 u = *reinterpret_cast<const uint2*>(vbf + (size_t)jc * C + c0);
            float4 cbv = *reinterpret_cast<const float4*>(&cb0[k * C + c0]);
            ac0.x = fmaf(mf * cbv.x, __uint_as_float((u.x & 0xFFFFu) << 16), ac0.x);
            ac0.y = fmaf(mf * cbv.y, __uint_as_float(u.x & 0xFFFF0000u), ac0.y);
            ac0.z = fmaf(mf * cbv.z, __uint_as_float((u.y & 0xFFFFu) << 16), ac0.z);
            ac0.w = fmaf(mf * cbv.w, __uint_as_float(u.y & 0xFFFF0000u), ac0.w);
        }
#pragma unroll 9
        for (int k = 0; k < 27; ++k) {
            int j = sidx[p][7 + k]; float mf = (j >= 0) ? 1.f : 0.f; int jc = (j >= 0) ? j : 0;
            uint2 u = *reinterpret_cast<const uint2*>(vbf + (size_t)jc * C + c0);
            float4 cbv = *reinterpret_cast<const float4*>(&cb1[k * C + c0]);
            ac1.x = fmaf(mf * cbv.x, __uint_as_float((u.x & 0xFFFFu) << 16), ac1.x);
            ac1.y = fmaf(mf * cbv.y, __uint_as_float(u.x & 0xFFFF0000u), ac1.y);
            ac1.z = fmaf(mf * cbv.z, __uint_as_float((u.y & 0xFFFFu) << 16), ac1.z);
            ac1.w = fmaf(mf * cbv.w, __uint_as_float(u.y & 0xFFFF0000u), ac1.w);
        }
#pragma unroll
        for (int k = 0; k < 7; ++k) {
            int j = sidx[p][34 + k]; float mf = (j >= 0) ? 1.f : 0.f; int jc = (j >= 0) ? j : 0;
            uint2 u = *reinterpret_cast<const uint2*>(vbf + (size_t)jc * C + c0);
            float4 cbv = *reinterpret_cast<const float4*>(&cb2[k * C + c0]);
            ac2.x = fmaf(mf * cbv.x, __uint_as_float((u.x & 0xFFFFu) << 16), ac2.x);
            ac2.y = fmaf(mf * cbv.y, __uint_as_float(u.x & 0xFFFF0000u), ac2.y);
            ac2.z = fmaf(mf * cbv.z, __uint_as_float((u.y & 0xFFFFu) << 16), ac2.z);
            ac2.w = fmaf(mf * cbv.w, __uint_as_float(u.y & 0xFFFF0000u), ac2.w);
        }
        int vg = cq >> 1;
        float a0 = sattn[p][vg][0], a1 = sattn[p][vg][1], a2 = sattn[p][vg][2];
        float4 o;
        o.x = a0 * ac0.x + a1 * ac1.x + a2 * ac2.x;
        o.y = a0 * ac0.y + a1 * ac1.y + a2 * ac2.y;
        o.z = a0 * ac0.z + a1 * ac1.z + a2 * ac2.z;
        o.w = a0 * ac0.w + a1 * ac1.w + a2 * ac2.w;
        *reinterpret_cast<float4*>(&outm[i * C + c0]) = o;
    }
}

// out = relu(buf*a + c) + x
__global__ __launch_bounds__(256) void final_bn_res(const float* __restrict__ buf,
                                                    const float* __restrict__ a,
                                                    const float* __restrict__ cc,
                                                    const float* __restrict__ x,
                                                    float* __restrict__ out, int total4) {
    for (int t = blockIdx.x * blockDim.x + threadIdx.x; t < total4; t += gridDim.x * blockDim.x) {
        float4 v = reinterpret_cast<const float4*>(buf)[t];
        float4 xv = reinterpret_cast<const float4*>(x)[t];
        int ch = (t * 4) & 127;
        v.x = fmaxf(fmaf(v.x, a[ch + 0], cc[ch + 0]), 0.f) + xv.x;
        v.y = fmaxf(fmaf(v.y, a[ch + 1], cc[ch + 1]), 0.f) + xv.y;
        v.z = fmaxf(fmaf(v.z, a[ch + 2], cc[ch + 2]), 0.f) + xv.z;
        v.w = fmaxf(fmaf(v.w, a[ch + 3], cc[ch + 3]), 0.f) + xv.w;
        reinterpret_cast<float4*>(out)[t] = v;
    }
}

extern "C" void kernel_launch(void* const* d_in, const int* in_sizes, int n_in,
                              void* d_out, int out_size, void* d_ws, size_t ws_size,
                              hipStream_t stream) {
    (void)in_sizes; (void)n_in; (void)out_size; (void)ws_size;
    const float* x    = (const float*)d_in[0];
    const float* v1_w = (const float*)d_in[1];
    const float* v1_g = (const float*)d_in[2];
    const float* v1_b = (const float*)d_in[3];
    const float* v2_w = (const float*)d_in[4];
    const float* v2_g = (const float*)d_in[5];
    const float* v2_b = (const float*)d_in[6];
    const float* q_w  = (const float*)d_in[7];
    const float* q_g  = (const float*)d_in[8];
    const float* q_b  = (const float*)d_in[9];
    const float* cb0  = (const float*)d_in[10];
    const float* cb1  = (const float*)d_in[11];
    const float* cb2  = (const float*)d_in[12];
    const float* out_w = (const float*)d_in[13];
    const float* out_g = (const float*)d_in[14];
    const float* out_b = (const float*)d_in[15];
    const int* nbrA = (const int*)d_in[16];   // cross2, K=7
    const int* nbrB = (const int*)d_in[17];   // cube,  K=27
    const int* nbrC = (const int*)d_in[18];   // cross3, K=7
    float* out = (float*)d_out;

    float* w = (float*)d_ws;
    size_t o = 0;
    float* bufA = w + o; o += (size_t)NN * C;
    float* bufB = w + o; o += (size_t)NN * C;
    float* bufQ = w + o; o += (size_t)NN * VEC;
    unsigned short* vbf = (unsigned short*)(w + o); o += (size_t)NN * C / 2;
    float* ps   = w + o; o += 256 * C;
    float* pq   = w + o; o += 256 * C;
    float* ps16 = w + o; o += 128 * VEC;
    float* pq16 = w + o; o += 128 * VEC;
    float* a1 = w + o; o += C;  float* c1 = w + o; o += C;
    float* a2 = w + o; o += C;  float* c2 = w + o; o += C;
    float* ao = w + o; o += C;  float* co = w + o; o += C;
    float* aq = w + o; o += VEC; float* cq = w + o; o += VEC;
    unsigned short* v1f = (unsigned short*)(w + o); o += (27 * 16384) / 2;
    unsigned short* v2f = (unsigned short*)(w + o); o += 16384 / 2;
    unsigned short* outf = (unsigned short*)(w + o); o += 16384 / 2;

    const int total4  = NN * C / 4;
    const int total4q = NN * VEC / 4;

    // pre-swizzle weights into MFMA B-fragment bf16
    wconv_bf16<<<27 * 64, 256, 0, stream>>>(v1_w, v1f);
    wconv_bf16<<<64, 256, 0, stream>>>(v2_w, v2f);
    wconv_bf16<<<64, 256, 0, stream>>>(out_w, outf);

    // conv1 (cube-27) -> bufA; BN stats
    conv1_mfma16<<<NN / 16, 256, 0, stream>>>(x, nbrB, (const bfx8*)v1f, bufA);
    stats_partial128<<<256, 256, 0, stream>>>(bufA, ps, pq);
    stats_final<<<1, 128, 0, stream>>>(ps, pq, 256, C, v1_g, v1_b, a1, c1);

    // v2 1x1 conv with fused BN+ReLU on input -> bufB; BN stats
    mm_bn_mfma<<<NN / 16, 256, 0, stream>>>(bufA, a1, c1, 1, (const bfx8*)v2f, bufB);
    stats_partial128<<<256, 256, 0, stream>>>(bufB, ps, pq);
    stats_final<<<1, 128, 0, stream>>>(ps, pq, 256, C, v2_g, v2_b, a2, c2);

    // v = relu(bn(bufB)) as bf16
    bnrelu_bf16<<<2048, 256, 0, stream>>>(bufB, a2, c2, vbf);

    // query branch
    qmm<<<NN / 16, 256, 0, stream>>>(x, q_w, bufQ);
    stats_partial16<<<128, 256, 0, stream>>>(bufQ, ps16, pq16);
    stats_final<<<1, 64, 0, stream>>>(ps16, pq16, 128, VEC, q_g, q_b, aq, cq);
    bn_relu_ip<<<1024, 256, 0, stream>>>(bufQ, aq, cq, total4q, 15);

    // fused expert convs + attention mix -> bufA (free after v2 mm)
    attn_fused8<<<NN / 8, 256, 0, stream>>>(vbf, bufQ, nbrA, nbrB, nbrC, cb0, cb1, cb2, bufA);

    // output 1x1 conv (no input BN) -> bufB; BN stats; final residual
    mm_bn_mfma<<<NN / 16, 256, 0, stream>>>(bufA, nullptr, nullptr, 0, (const bfx8*)outf, bufB);
    stats_partial128<<<256, 256, 0, stream>>>(bufB, ps, pq);
    stats_final<<<1, 128, 0, stream>>>(ps, pq, 256, C, out_g, out_b, ao, co);
    final_bn_res<<<2048, 256, 0, stream>>>(bufB, ao, co, x, out, total4);
}

// Round 4
// 551.661 us; speedup vs baseline: 4.1962x; 1.5449x over previous
//
#include <hip/hip_runtime.h>

#define NN 100000
#define C 128
#define VEC 16
#define AROW 136   // padded LDS row stride (ushorts)

typedef __bf16 bfx8 __attribute__((ext_vector_type(8)));
typedef float f32x4 __attribute__((ext_vector_type(4)));

__device__ inline unsigned pack_bf2(float a, float b) {
    unsigned ua = __float_as_uint(a);
    unsigned ub = __float_as_uint(b);
    ua = (ua + 0x7fffu + ((ua >> 16) & 1u)) >> 16;
    ub = (ub + 0x7fffu + ((ub >> 16) & 1u)) >> 16;
    return ua | (ub << 16);
}

// ---------------------------------------------------------------------------
// Pre-swizzle W [KT][128][128] fp32 -> bf16 in exact MFMA B-fragment order.
// ---------------------------------------------------------------------------
__global__ __launch_bounds__(256) void wconv_bf16(const float* __restrict__ W,
                                                  unsigned short* __restrict__ Wf) {
    int F = blockIdx.x * 256 + threadIdx.x;
    int e = F & 7, l = (F >> 3) & 63, nt = (F >> 9) & 7, ks = (F >> 12) & 3, kt = F >> 14;
    int cin = ks * 32 + (l >> 4) * 8 + e;
    int cout = nt * 16 + (l & 15);
    float v = W[((size_t)kt * C + cin) * C + cout];
    unsigned u = __float_as_uint(v);
    Wf[F] = (unsigned short)((u + 0x7fffu + ((u >> 16) & 1u)) >> 16);
}

// zero pad rows (index NN) for q and v buffers
__global__ void zeropad(float* __restrict__ qz, unsigned short* __restrict__ vz) {
    int t = threadIdx.x;
    if (t < VEC) qz[t] = 0.f;
    if (t < C) vz[t] = 0;
}

// ---------------------------------------------------------------------------
// Sparse 27-tap conv, 16-point tile. Upfront index load + tap bitmask;
// one sync per valid tap; double-buffered A staging overlapped with MFMA.
// Fused per-block BN partial stats.
// ---------------------------------------------------------------------------
__global__ __launch_bounds__(256) void conv1_mfma16(const float* __restrict__ x,
                                                    const int* __restrict__ nbr,
                                                    const bfx8* __restrict__ Wf,
                                                    float* __restrict__ out,
                                                    float* __restrict__ psb,
                                                    float* __restrict__ pqb) {
    const int tid = threadIdx.x, l = tid & 63, w = tid >> 6;
    const int rr = tid >> 4, gg = tid & 15;
    const int base = blockIdx.x * 16;
    __shared__ int sjall[432];
    __shared__ unsigned smk;
    __shared__ unsigned short Abuf[2][16 * AROW];
    __shared__ float outt[16 * 132];

    if (tid == 0) smk = 0u;
    __syncthreads();
    for (int t = tid; t < 432; t += 256) {
        int kt = t >> 4, r = t & 15;
        int j = nbr[(size_t)kt * NN + base + r];
        sjall[t] = j;
        if (j >= 0) atomicOr(&smk, 1u << kt);
    }
    __syncthreads();
    unsigned um = smk;

    f32x4 acc0 = {0.f, 0.f, 0.f, 0.f};
    f32x4 acc1 = {0.f, 0.f, 0.f, 0.f};

    if (um) {
        int kt = (int)__builtin_ctz(um);
        unsigned rem = um & (um - 1);
        {   // prologue: stage first valid tap into Abuf[0]
            int j = sjall[kt * 16 + rr];
            uint4 pk = {0u, 0u, 0u, 0u};
            if (j >= 0) {
                const float* xr = x + (size_t)j * C + gg * 8;
                float4 xa = *reinterpret_cast<const float4*>(xr);
                float4 xb = *reinterpret_cast<const float4*>(xr + 4);
                pk.x = pack_bf2(xa.x, xa.y); pk.y = pack_bf2(xa.z, xa.w);
                pk.z = pack_bf2(xb.x, xb.y); pk.w = pack_bf2(xb.z, xb.w);
            }
            *reinterpret_cast<uint4*>(&Abuf[0][rr * AROW + gg * 8]) = pk;
        }
        int cur = 0;
        while (1) {
            int ktn = rem ? (int)__builtin_ctz(rem) : -1;
            __syncthreads();
            // issue next-tap global loads early (hide under MFMA)
            float4 xa, xb; int jn = -1;
            if (ktn >= 0) {
                jn = sjall[ktn * 16 + rr];
                if (jn >= 0) {
                    const float* xr = x + (size_t)jn * C + gg * 8;
                    xa = *reinterpret_cast<const float4*>(xr);
                    xb = *reinterpret_cast<const float4*>(xr + 4);
                }
            }
            // MFMA on current buffer
            const unsigned short* arow = &Abuf[cur][(l & 15) * AROW + (l >> 4) * 8];
#pragma unroll
            for (int ks = 0; ks < 4; ++ks) {
                bfx8 af = *reinterpret_cast<const bfx8*>(arow + ks * 32);
                bfx8 b0 = Wf[((kt * 4 + ks) * 8 + 2 * w) * 64 + l];
                bfx8 b1 = Wf[((kt * 4 + ks) * 8 + 2 * w + 1) * 64 + l];
                acc0 = __builtin_amdgcn_mfma_f32_16x16x32_bf16(af, b0, acc0, 0, 0, 0);
                acc1 = __builtin_amdgcn_mfma_f32_16x16x32_bf16(af, b1, acc1, 0, 0, 0);
            }
            if (ktn < 0) break;
            // pack + LDS write for next tap
            uint4 pk = {0u, 0u, 0u, 0u};
            if (jn >= 0) {
                pk.x = pack_bf2(xa.x, xa.y); pk.y = pack_bf2(xa.z, xa.w);
                pk.z = pack_bf2(xb.x, xb.y); pk.w = pack_bf2(xb.z, xb.w);
            }
            *reinterpret_cast<uint4*>(&Abuf[cur ^ 1][rr * AROW + gg * 8]) = pk;
            kt = ktn; rem &= rem - 1; cur ^= 1;
        }
    }
    __syncthreads();
#pragma unroll
    for (int r = 0; r < 4; ++r) {
        int row = (l >> 4) * 4 + r;
        outt[row * 132 + w * 32 + (l & 15)] = acc0[r];
        outt[row * 132 + w * 32 + 16 + (l & 15)] = acc1[r];
    }
    __syncthreads();
    {
        float4 v0 = *reinterpret_cast<float4*>(&outt[rr * 132 + gg * 8]);
        float4 v1 = *reinterpret_cast<float4*>(&outt[rr * 132 + gg * 8 + 4]);
        float* op = out + (size_t)(base + rr) * C + gg * 8;
        *reinterpret_cast<float4*>(op) = v0;
        *reinterpret_cast<float4*>(op + 4) = v1;
    }
    if (tid < 128) {   // fused BN partial stats over the 16-row tile
        float s = 0.f, q = 0.f;
#pragma unroll
        for (int r = 0; r < 16; ++r) { float v = outt[r * 132 + tid]; s += v; q += v * v; }
        psb[(size_t)blockIdx.x * C + tid] = s;
        pqb[(size_t)blockIdx.x * C + tid] = q;
    }
}

// ---------------------------------------------------------------------------
// Dense [N,128]@[128,128] MFMA matmul, optional fused input BN+ReLU,
// fused per-block BN partial stats on the OUTPUT.
// ---------------------------------------------------------------------------
__global__ __launch_bounds__(256) void mm_bn_mfma(const float* __restrict__ in,
                                                  const float* __restrict__ a,
                                                  const float* __restrict__ cc,
                                                  int dorelu,
                                                  const bfx8* __restrict__ Wf,
                                                  float* __restrict__ out,
                                                  float* __restrict__ psb,
                                                  float* __restrict__ pqb) {
    const int tid = threadIdx.x, l = tid & 63, w = tid >> 6;
    const int rr = tid >> 4, gg = tid & 15;
    const size_t base = (size_t)blockIdx.x * 16;
    __shared__ unsigned short Ash[16 * AROW];
    __shared__ float outt[16 * 132];
    {
        const float* xr = in + (base + rr) * C + gg * 8;
        float4 xa = *reinterpret_cast<const float4*>(xr);
        float4 xb = *reinterpret_cast<const float4*>(xr + 4);
        if (dorelu) {
            float4 a4 = *reinterpret_cast<const float4*>(&a[gg * 8]);
            float4 a4b = *reinterpret_cast<const float4*>(&a[gg * 8 + 4]);
            float4 c4 = *reinterpret_cast<const float4*>(&cc[gg * 8]);
            float4 c4b = *reinterpret_cast<const float4*>(&cc[gg * 8 + 4]);
            xa.x = fmaxf(fmaf(xa.x, a4.x, c4.x), 0.f);
            xa.y = fmaxf(fmaf(xa.y, a4.y, c4.y), 0.f);
            xa.z = fmaxf(fmaf(xa.z, a4.z, c4.z), 0.f);
            xa.w = fmaxf(fmaf(xa.w, a4.w, c4.w), 0.f);
            xb.x = fmaxf(fmaf(xb.x, a4b.x, c4b.x), 0.f);
            xb.y = fmaxf(fmaf(xb.y, a4b.y, c4b.y), 0.f);
            xb.z = fmaxf(fmaf(xb.z, a4b.z, c4b.z), 0.f);
            xb.w = fmaxf(fmaf(xb.w, a4b.w, c4b.w), 0.f);
        }
        uint4 pk;
        pk.x = pack_bf2(xa.x, xa.y); pk.y = pack_bf2(xa.z, xa.w);
        pk.z = pack_bf2(xb.x, xb.y); pk.w = pack_bf2(xb.z, xb.w);
        *reinterpret_cast<uint4*>(&Ash[rr * AROW + gg * 8]) = pk;
    }
    __syncthreads();
    f32x4 acc0 = {0.f, 0.f, 0.f, 0.f};
    f32x4 acc1 = {0.f, 0.f, 0.f, 0.f};
    const unsigned short* arow = &Ash[(l & 15) * AROW + (l >> 4) * 8];
#pragma unroll
    for (int ks = 0; ks < 4; ++ks) {
        bfx8 af = *reinterpret_cast<const bfx8*>(arow + ks * 32);
        bfx8 b0 = Wf[(ks * 8 + 2 * w) * 64 + l];
        bfx8 b1 = Wf[(ks * 8 + 2 * w + 1) * 64 + l];
        acc0 = __builtin_amdgcn_mfma_f32_16x16x32_bf16(af, b0, acc0, 0, 0, 0);
        acc1 = __builtin_amdgcn_mfma_f32_16x16x32_bf16(af, b1, acc1, 0, 0, 0);
    }
#pragma unroll
    for (int r = 0; r < 4; ++r) {
        int row = (l >> 4) * 4 + r;
        outt[row * 132 + w * 32 + (l & 15)] = acc0[r];
        outt[row * 132 + w * 32 + 16 + (l & 15)] = acc1[r];
    }
    __syncthreads();
    {
        float4 v0 = *reinterpret_cast<float4*>(&outt[rr * 132 + gg * 8]);
        float4 v1 = *reinterpret_cast<float4*>(&outt[rr * 132 + gg * 8 + 4]);
        float* op = out + (base + rr) * C + gg * 8;
        *reinterpret_cast<float4*>(op) = v0;
        *reinterpret_cast<float4*>(op + 4) = v1;
    }
    if (tid < 128) {
        float s = 0.f, q = 0.f;
#pragma unroll
        for (int r = 0; r < 16; ++r) { float v = outt[r * 132 + tid]; s += v; q += v * v; }
        psb[(size_t)blockIdx.x * C + tid] = s;
        pqb[(size_t)blockIdx.x * C + tid] = q;
    }
}

// ---------------------------------------------------------------------------
// q = x @ q_w  ([N,128] @ [128,16])
// ---------------------------------------------------------------------------
__global__ __launch_bounds__(256) void qmm(const float* __restrict__ x,
                                           const float* __restrict__ qw,
                                           float* __restrict__ outq) {
    const int v = threadIdx.x & 15, p = threadIdx.x >> 4;
    const size_t i = (size_t)blockIdx.x * 16 + p;
    float acc = 0.f;
    for (int cin0 = 0; cin0 < C; cin0 += 4) {
        float4 xv = *reinterpret_cast<const float4*>(x + i * C + cin0);
        acc += xv.x * qw[(cin0 + 0) * VEC + v] + xv.y * qw[(cin0 + 1) * VEC + v]
             + xv.z * qw[(cin0 + 2) * VEC + v] + xv.w * qw[(cin0 + 3) * VEC + v];
    }
    outq[i * VEC + v] = acc;
}

// ---------------------------------------------------------------------------
// Reductions
// ---------------------------------------------------------------------------
__global__ __launch_bounds__(256) void stats_mid128(const float* __restrict__ psb,
                                                    const float* __restrict__ pqb,
                                                    int rows,
                                                    float* __restrict__ ps2,
                                                    float* __restrict__ pq2) {
    const int ch = threadIdx.x & 127, half = threadIdx.x >> 7;
    float s = 0.f, q = 0.f;
    for (int i = blockIdx.x * 2 + half; i < rows; i += 128) {
        s += psb[(size_t)i * C + ch];
        q += pqb[(size_t)i * C + ch];
    }
    __shared__ float ls[256], lq[256];
    ls[threadIdx.x] = s; lq[threadIdx.x] = q;
    __syncthreads();
    if (threadIdx.x < 128) {
        ps2[blockIdx.x * C + ch] = ls[threadIdx.x] + ls[threadIdx.x + 128];
        pq2[blockIdx.x * C + ch] = lq[threadIdx.x] + lq[threadIdx.x + 128];
    }
}

__global__ __launch_bounds__(256) void stats_partial16(const float* __restrict__ buf,
                                                       float* __restrict__ ps,
                                                       float* __restrict__ pq) {
    const int ch = threadIdx.x & 15, grp = threadIdx.x >> 4;
    float s = 0.f, q = 0.f;
    for (int i = blockIdx.x * 16 + grp; i < NN; i += gridDim.x * 16) {
        float val = buf[(size_t)i * VEC + ch];
        s += val; q += val * val;
    }
    __shared__ float ls[256], lq[256];
    ls[threadIdx.x] = s; lq[threadIdx.x] = q;
    __syncthreads();
    if (threadIdx.x < 16) {
        float ss = 0.f, qq = 0.f;
        for (int g2 = 0; g2 < 16; ++g2) { ss += ls[g2 * 16 + ch]; qq += lq[g2 * 16 + ch]; }
        ps[blockIdx.x * VEC + ch] = ss; pq[blockIdx.x * VEC + ch] = qq;
    }
}

__global__ void stats_final(const float* __restrict__ ps, const float* __restrict__ pq,
                            int nb, int cdim,
                            const float* __restrict__ g, const float* __restrict__ b,
                            float* __restrict__ a, float* __restrict__ cc) {
    int ch = threadIdx.x;
    if (ch >= cdim) return;
    float s = 0.f, q = 0.f;
    for (int i = 0; i < nb; ++i) { s += ps[i * cdim + ch]; q += pq[i * cdim + ch]; }
    float m = s / (float)NN;
    float var = q / (float)NN - m * m;
    var = fmaxf(var, 0.f);
    float rs = rsqrtf(var + 1e-5f);
    float av = g[ch] * rs;
    a[ch] = av;
    cc[ch] = b[ch] - m * av;
}

// in-place y = relu(y*a[ch] + c[ch]); mask = channel mask (pow2-1)
__global__ __launch_bounds__(256) void bn_relu_ip(float* __restrict__ buf,
                                                  const float* __restrict__ a,
                                                  const float* __restrict__ cc,
                                                  int total4, int mask) {
    for (int t = blockIdx.x * blockDim.x + threadIdx.x; t < total4; t += gridDim.x * blockDim.x) {
        float4 v = reinterpret_cast<float4*>(buf)[t];
        int ch = (t * 4) & mask;
        v.x = fmaxf(fmaf(v.x, a[ch + 0], cc[ch + 0]), 0.f);
        v.y = fmaxf(fmaf(v.y, a[ch + 1], cc[ch + 1]), 0.f);
        v.z = fmaxf(fmaf(v.z, a[ch + 2], cc[ch + 2]), 0.f);
        v.w = fmaxf(fmaf(v.w, a[ch + 3], cc[ch + 3]), 0.f);
        reinterpret_cast<float4*>(buf)[t] = v;
    }
}

// BN+ReLU applied, output bf16 (v buffer for the attention stage)
__global__ __launch_bounds__(256) void bnrelu_bf16(const float* __restrict__ in,
                                                   const float* __restrict__ a,
                                                   const float* __restrict__ cc,
                                                   unsigned short* __restrict__ outh) {
    const int total8 = NN * C / 8;
    for (int t = blockIdx.x * 256 + threadIdx.x; t < total8; t += gridDim.x * 256) {
        int ch = (t * 8) & 127;
        const float* xr = in + (size_t)t * 8;
        float4 xa = *reinterpret_cast<const float4*>(xr);
        float4 xb = *reinterpret_cast<const float4*>(xr + 4);
        float4 a4 = *reinterpret_cast<const float4*>(&a[ch]);
        float4 a4b = *reinterpret_cast<const float4*>(&a[ch + 4]);
        float4 c4 = *reinterpret_cast<const float4*>(&cc[ch]);
        float4 c4b = *reinterpret_cast<const float4*>(&cc[ch + 4]);
        xa.x = fmaxf(fmaf(xa.x, a4.x, c4.x), 0.f);
        xa.y = fmaxf(fmaf(xa.y, a4.y, c4.y), 0.f);
        xa.z = fmaxf(fmaf(xa.z, a4.z, c4.z), 0.f);
        xa.w = fmaxf(fmaf(xa.w, a4.w, c4.w), 0.f);
        xb.x = fmaxf(fmaf(xb.x, a4b.x, c4b.x), 0.f);
        xb.y = fmaxf(fmaf(xb.y, a4b.y, c4b.y), 0.f);
        xb.z = fmaxf(fmaf(xb.z, a4b.z, c4b.z), 0.f);
        xb.w = fmaxf(fmaf(xb.w, a4b.w, c4b.w), 0.f);
        uint4 pk;
        pk.x = pack_bf2(xa.x, xa.y); pk.y = pack_bf2(xa.z, xa.w);
        pk.z = pack_bf2(xb.x, xb.y); pk.w = pack_bf2(xb.z, xb.w);
        *reinterpret_cast<uint4*>(&outh[(size_t)t * 8]) = pk;
    }
}

// ---------------------------------------------------------------------------
// Fused attention: 16 points / 256-thread block, zero-row trick (index NN
// = zero row), 8 channels/thread via uint4 bf16 loads. No mask arithmetic.
// ---------------------------------------------------------------------------
__global__ __launch_bounds__(256) void attn_fused16(const unsigned short* __restrict__ vbf,
                                                    const float* __restrict__ qbuf,
                                                    const int* __restrict__ nA,
                                                    const int* __restrict__ nB,
                                                    const int* __restrict__ nC,
                                                    const float* __restrict__ cb0,
                                                    const float* __restrict__ cb1,
                                                    const float* __restrict__ cb2,
                                                    float* __restrict__ outm) {
    const int tid = threadIdx.x;
    const int base = blockIdx.x * 16;     // grid exact: 6250*16 = 100000
    __shared__ int sidx[16][48];
    __shared__ float scnt[16][3];
    __shared__ float sattn[16][16][3];

    for (int t = tid; t < 656; t += 256) {
        int k = t >> 4, p = t & 15;
        int i = base + p;
        int j;
        if (k < 7)       j = nA[(size_t)k * NN + i];
        else if (k < 34) j = nB[(size_t)(k - 7) * NN + i];
        else             j = nC[(size_t)(k - 34) * NN + i];
        sidx[p][k] = (j >= 0) ? j : NN;
    }
    __syncthreads();
    if (tid < 48) {
        int p = tid & 15, e = tid >> 4;
        int k0 = (e == 0) ? 0 : ((e == 1) ? 7 : 34);
        int k1 = (e == 0) ? 7 : ((e == 1) ? 34 : 41);
        int cnt = 0;
        for (int k = k0; k < k1; ++k) cnt += (sidx[p][k] != NN);
        scnt[p][e] = (float)(cnt > 0 ? cnt : 1);
    }
    __syncthreads();
    {   // scores + softmax: all 256 threads (16p x 16v)
        int p = tid >> 4, v = tid & 15;
        float qi = qbuf[(size_t)(base + p) * VEC + v];
        float a0 = 0.f, a1 = 0.f, a2 = 0.f;
#pragma unroll
        for (int k = 0; k < 7; ++k)  a0 += qbuf[(size_t)sidx[p][k] * VEC + v];
#pragma unroll 9
        for (int k = 7; k < 34; ++k) a1 += qbuf[(size_t)sidx[p][k] * VEC + v];
#pragma unroll
        for (int k = 34; k < 41; ++k) a2 += qbuf[(size_t)sidx[p][k] * VEC + v];
        float s0 = qi * a0 / scnt[p][0];
        float s1 = qi * a1 / scnt[p][1];
        float s2 = qi * a2 / scnt[p][2];
        float mx = fmaxf(s0, fmaxf(s1, s2));
        float e0 = __expf(s0 - mx), e1 = __expf(s1 - mx), e2 = __expf(s2 - mx);
        float inv = 1.f / (e0 + e1 + e2);
        sattn[p][v][0] = e0 * inv; sattn[p][v][1] = e1 * inv; sattn[p][v][2] = e2 * inv;
    }
    __syncthreads();
    {   // channelwise mix: 16p x 16 lanes x 8 channels
        int p = tid >> 4, g = tid & 15, c0 = g * 8;
        float A0[8], A1[8], A2[8];
#pragma unroll
        for (int c = 0; c < 8; ++c) { A0[c] = 0.f; A1[c] = 0.f; A2[c] = 0.f; }
#pragma unroll
        for (int k = 0; k < 7; ++k) {
            int jc = sidx[p][k];
            uint4 u = *reinterpret_cast<const uint4*>(vbf + (size_t)jc * C + c0);
            float4 ca = *reinterpret_cast<const float4*>(&cb0[k * C + c0]);
            float4 cb = *reinterpret_cast<const float4*>(&cb0[k * C + c0 + 4]);
            A0[0] = fmaf(ca.x, __uint_as_float(u.x << 16), A0[0]);
            A0[1] = fmaf(ca.y, __uint_as_float(u.x & 0xffff0000u), A0[1]);
            A0[2] = fmaf(ca.z, __uint_as_float(u.y << 16), A0[2]);
            A0[3] = fmaf(ca.w, __uint_as_float(u.y & 0xffff0000u), A0[3]);
            A0[4] = fmaf(cb.x, __uint_as_float(u.z << 16), A0[4]);
            A0[5] = fmaf(cb.y, __uint_as_float(u.z & 0xffff0000u), A0[5]);
            A0[6] = fmaf(cb.z, __uint_as_float(u.w << 16), A0[6]);
            A0[7] = fmaf(cb.w, __uint_as_float(u.w & 0xffff0000u), A0[7]);
        }
#pragma unroll 9
        for (int k = 7; k < 34; ++k) {
            int jc = sidx[p][k];
            uint4 u = *reinterpret_cast<const uint4*>(vbf + (size_t)jc * C + c0);
            float4 ca = *reinterpret_cast<const float4*>(&cb1[(k - 7) * C + c0]);
            float4 cb = *reinterpret_cast<const float4*>(&cb1[(k - 7) * C + c0 + 4]);
            A1[0] = fmaf(ca.x, __uint_as_float(u.x << 16), A1[0]);
            A1[1] = fmaf(ca.y, __uint_as_float(u.x & 0xffff0000u), A1[1]);
            A1[2] = fmaf(ca.z, __uint_as_float(u.y << 16), A1[2]);
            A1[3] = fmaf(ca.w, __uint_as_float(u.y & 0xffff0000u), A1[3]);
            A1[4] = fmaf(cb.x, __uint_as_float(u.z << 16), A1[4]);
            A1[5] = fmaf(cb.y, __uint_as_float(u.z & 0xffff0000u), A1[5]);
            A1[6] = fmaf(cb.z, __uint_as_float(u.w << 16), A1[6]);
            A1[7] = fmaf(cb.w, __uint_as_float(u.w & 0xffff0000u), A1[7]);
        }
#pragma unroll
        for (int k = 34; k < 41; ++k) {
            int jc = sidx[p][k];
            uint4 u = *reinterpret_cast<const uint4*>(vbf + (size_t)jc * C + c0);
            float4 ca = *reinterpret_cast<const float4*>(&cb2[(k - 34) * C + c0]);
            float4 cb = *reinterpret_cast<const float4*>(&cb2[(k - 34) * C + c0 + 4]);
            A2[0] = fmaf(ca.x, __uint_as_float(u.x << 16), A2[0]);
            A2[1] = fmaf(ca.y, __uint_as_float(u.x & 0xffff0000u), A2[1]);
            A2[2] = fmaf(ca.z, __uint_as_float(u.y << 16), A2[2]);
            A2[3] = fmaf(ca.w, __uint_as_float(u.y & 0xffff0000u), A2[3]);
            A2[4] = fmaf(cb.x, __uint_as_float(u.z << 16), A2[4]);
            A2[5] = fmaf(cb.y, __uint_as_float(u.z & 0xffff0000u), A2[5]);
            A2[6] = fmaf(cb.z, __uint_as_float(u.w << 16), A2[6]);
            A2[7] = fmaf(cb.w, __uint_as_float(u.w & 0xffff0000u), A2[7]);
        }
        float w0 = sattn[p][g][0], w1 = sattn[p][g][1], w2 = sattn[p][g][2];
        float o[8];
#pragma unroll
        for (int c = 0; c < 8; ++c) o[c] = w0 * A0[c] + w1 * A1[c] + w2 * A2[c];
        float* op = &outm[(size_t)(base + p) * C + c0];
        float4 o0 = {o[0], o[1], o[2], o[3]};
        float4 o1 = {o[4], o[5], o[6], o[7]};
        *reinterpret_cast<float4*>(op) = o0;
        *reinterpret_cast<float4*>(op + 4) = o1;
    }
}

// out = relu(buf*a + c) + x
__global__ __launch_bounds__(256) void final_bn_res(const float* __restrict__ buf,
                                                    const float* __restrict__ a,
                                                    const float* __restrict__ cc,
                                                    const float* __restrict__ x,
                                                    float* __restrict__ out, int total4) {
    for (int t = blockIdx.x * blockDim.x + threadIdx.x; t < total4; t += gridDim.x * blockDim.x) {
        float4 v = reinterpret_cast<const float4*>(buf)[t];
        float4 xv = reinterpret_cast<const float4*>(x)[t];
        int ch = (t * 4) & 127;
        v.x = fmaxf(fmaf(v.x, a[ch + 0], cc[ch + 0]), 0.f) + xv.x;
        v.y = fmaxf(fmaf(v.y, a[ch + 1], cc[ch + 1]), 0.f) + xv.y;
        v.z = fmaxf(fmaf(v.z, a[ch + 2], cc[ch + 2]), 0.f) + xv.z;
        v.w = fmaxf(fmaf(v.w, a[ch + 3], cc[ch + 3]), 0.f) + xv.w;
        reinterpret_cast<float4*>(out)[t] = v;
    }
}

extern "C" void kernel_launch(void* const* d_in, const int* in_sizes, int n_in,
                              void* d_out, int out_size, void* d_ws, size_t ws_size,
                              hipStream_t stream) {
    (void)in_sizes; (void)n_in; (void)out_size; (void)ws_size;
    const float* x    = (const float*)d_in[0];
    const float* v1_w = (const float*)d_in[1];
    const float* v1_g = (const float*)d_in[2];
    const float* v1_b = (const float*)d_in[3];
    const float* v2_w = (const float*)d_in[4];
    const float* v2_g = (const float*)d_in[5];
    const float* v2_b = (const float*)d_in[6];
    const float* q_w  = (const float*)d_in[7];
    const float* q_g  = (const float*)d_in[8];
    const float* q_b  = (const float*)d_in[9];
    const float* cb0  = (const float*)d_in[10];
    const float* cb1  = (const float*)d_in[11];
    const float* cb2  = (const float*)d_in[12];
    const float* out_w = (const float*)d_in[13];
    const float* out_g = (const float*)d_in[14];
    const float* out_b = (const float*)d_in[15];
    const int* nbrA = (const int*)d_in[16];   // cross2, K=7
    const int* nbrB = (const int*)d_in[17];   // cube,  K=27
    const int* nbrC = (const int*)d_in[18];   // cross3, K=7
    float* out = (float*)d_out;

    float* w = (float*)d_ws;
    size_t o = 0;
    float* bufA = w + o; o += (size_t)NN * C;
    float* bufB = w + o; o += (size_t)NN * C;
    float* bufQ = w + o; o += (size_t)(NN + 1) * VEC;           // +1 zero row
    unsigned short* vbf = (unsigned short*)(w + o); o += (size_t)(NN + 1) * C / 2;
    float* psb  = w + o; o += (size_t)6250 * C;
    float* pqb  = w + o; o += (size_t)6250 * C;
    float* ps2  = w + o; o += 64 * C;
    float* pq2  = w + o; o += 64 * C;
    float* ps16 = w + o; o += 128 * VEC;
    float* pq16 = w + o; o += 128 * VEC;
    float* a1 = w + o; o += C;  float* c1 = w + o; o += C;
    float* a2 = w + o; o += C;  float* c2 = w + o; o += C;
    float* ao = w + o; o += C;  float* co = w + o; o += C;
    float* aq = w + o; o += VEC; float* cq = w + o; o += VEC;
    unsigned short* v1f = (unsigned short*)(w + o); o += (27 * 16384) / 2;
    unsigned short* v2f = (unsigned short*)(w + o); o += 16384 / 2;
    unsigned short* outf = (unsigned short*)(w + o); o += 16384 / 2;

    const int total4  = NN * C / 4;
    const int total4q = NN * VEC / 4;

    // weight pre-swizzles + zero pad rows
    wconv_bf16<<<27 * 64, 256, 0, stream>>>(v1_w, v1f);
    wconv_bf16<<<64, 256, 0, stream>>>(v2_w, v2f);
    wconv_bf16<<<64, 256, 0, stream>>>(out_w, outf);
    zeropad<<<1, 128, 0, stream>>>(bufQ + (size_t)NN * VEC, vbf + (size_t)NN * C);

    // conv1 (cube-27) -> bufA, fused stats
    conv1_mfma16<<<NN / 16, 256, 0, stream>>>(x, nbrB, (const bfx8*)v1f, bufA, psb, pqb);
    stats_mid128<<<64, 256, 0, stream>>>(psb, pqb, 6250, ps2, pq2);
    stats_final<<<1, 128, 0, stream>>>(ps2, pq2, 64, C, v1_g, v1_b, a1, c1);

    // v2 1x1 conv with fused input BN+ReLU -> bufB, fused stats
    mm_bn_mfma<<<NN / 16, 256, 0, stream>>>(bufA, a1, c1, 1, (const bfx8*)v2f, bufB, psb, pqb);
    stats_mid128<<<64, 256, 0, stream>>>(psb, pqb, 6250, ps2, pq2);
    stats_final<<<1, 128, 0, stream>>>(ps2, pq2, 64, C, v2_g, v2_b, a2, c2);

    // v = relu(bn(bufB)) as bf16
    bnrelu_bf16<<<2048, 256, 0, stream>>>(bufB, a2, c2, vbf);

    // query branch
    qmm<<<NN / 16, 256, 0, stream>>>(x, q_w, bufQ);
    stats_partial16<<<128, 256, 0, stream>>>(bufQ, ps16, pq16);
    stats_final<<<1, 64, 0, stream>>>(ps16, pq16, 128, VEC, q_g, q_b, aq, cq);
    bn_relu_ip<<<1024, 256, 0, stream>>>(bufQ, aq, cq, total4q, 15);

    // fused expert convs + attention mix -> bufA
    attn_fused16<<<NN / 16, 256, 0, stream>>>(vbf, bufQ, nbrA, nbrB, nbrC, cb0, cb1, cb2, bufA);

    // output 1x1 conv -> bufB, fused stats; final residual
    mm_bn_mfma<<<NN / 16, 256, 0, stream>>>(bufA, nullptr, nullptr, 0, (const bfx8*)outf, bufB, psb, pqb);
    stats_mid128<<<64, 256, 0, stream>>>(psb, pqb, 6250, ps2, pq2);
    stats_final<<<1, 128, 0, stream>>>(ps2, pq2, 64, C, out_g, out_b, ao, co);
    final_bn_res<<<2048, 256, 0, stream>>>(bufB, ao, co, x, out, total4);
}

// Round 5
// 512.014 us; speedup vs baseline: 4.5212x; 1.0774x over previous
//
#include <hip/hip_runtime.h>

#define NN 100000
#define C 128
#define VEC 16
#define AROW 136   // padded LDS row stride (ushorts)
#define GCAP 240000

typedef __bf16 bfx8 __attribute__((ext_vector_type(8)));
typedef float f32x4 __attribute__((ext_vector_type(4)));

__device__ inline unsigned pack_bf2(float a, float b) {
    unsigned ua = __float_as_uint(a);
    unsigned ub = __float_as_uint(b);
    ua = (ua + 0x7fffu + ((ua >> 16) & 1u)) >> 16;
    ub = (ub + 0x7fffu + ((ub >> 16) & 1u)) >> 16;
    return ua | (ub << 16);
}
__device__ inline unsigned short bf1(float a) {
    unsigned u = __float_as_uint(a);
    return (unsigned short)((u + 0x7fffu + ((u >> 16) & 1u)) >> 16);
}

// ---------------------------------------------------------------------------
// Prep: all weight pre-swizzles (MFMA B-fragment bf16) + zero pad rows.
// Wf[(((kt*4+ks)*8+nt)*64+l)*8+e] = bf16(W[kt][ks*32+(l>>4)*8+e][nt*16+(l&15)])
// ---------------------------------------------------------------------------
__device__ inline void wconv_body(const float* __restrict__ W, unsigned short* __restrict__ Wf, int F) {
    int e = F & 7, l = (F >> 3) & 63, nt = (F >> 9) & 7, ks = (F >> 12) & 3, kt = F >> 14;
    int cin = ks * 32 + (l >> 4) * 8 + e;
    int cout = nt * 16 + (l & 15);
    Wf[F] = bf1(W[((size_t)kt * C + cin) * C + cout]);
}

__global__ __launch_bounds__(256) void prep(const float* __restrict__ v1w, const float* __restrict__ v2w,
                                            const float* __restrict__ outw,
                                            unsigned short* __restrict__ v1f, unsigned short* __restrict__ v2f,
                                            unsigned short* __restrict__ outf,
                                            float* __restrict__ qz, unsigned short* __restrict__ vz) {
    int b = blockIdx.x, tid = threadIdx.x;
    if (b < 1728)       wconv_body(v1w, v1f, b * 256 + tid);
    else if (b < 1792)  wconv_body(v2w, v2f, (b - 1728) * 256 + tid);
    else if (b < 1856)  wconv_body(outw, outf, (b - 1792) * 256 + tid);
    else { if (tid < VEC) qz[tid] = 0.f; if (tid < C) vz[tid] = 0; }
}

// ---------------------------------------------------------------------------
// compactA: per-tap compacted pair lists. Block = (tap k, 2048-point chunk).
// Deterministic output: slot position never affects values (see convC).
// ---------------------------------------------------------------------------
__global__ __launch_bounds__(256) void compactA(const int* __restrict__ nbr, int* __restrict__ cnt,
                                                int* __restrict__ slotmap, int* __restrict__ pairs,
                                                unsigned* __restrict__ maskbuf) {
    const int k = blockIdx.x / 49, cb = blockIdx.x % 49, tid = threadIdx.x;
    const int i0 = cb * 2048 + tid * 8;
    int j[8]; int lc = 0;
#pragma unroll
    for (int t = 0; t < 8; ++t) {
        int i = i0 + t;
        j[t] = (i < NN) ? nbr[(size_t)k * NN + i] : -1;
        lc += (j[t] >= 0);
    }
    __shared__ int ls[256]; __shared__ int sbase;
    ls[tid] = lc; __syncthreads();
    for (int off = 1; off < 256; off <<= 1) {
        int v = (tid >= off) ? ls[tid - off] : 0;
        __syncthreads();
        ls[tid] += v;
        __syncthreads();
    }
    if (tid == 255) sbase = atomicAdd(&cnt[k], ls[255]);
    __syncthreads();
    int slot = sbase + ls[tid] - lc;
    for (int t = 0; t < 8; ++t) {
        int i = i0 + t; if (i >= NN) break;
        int s = -1;
        if (j[t] >= 0) {
            s = slot++;
            pairs[(size_t)k * NN + s] = j[t];
            atomicOr(&maskbuf[i], 1u << k);
        }
        slotmap[(size_t)k * NN + i] = s;
    }
}

// hdr: [0..26]=cnt, [32..59]=chunkoff (28), [64..90]=goff (27)
__global__ void prefixA2(int* __restrict__ hdr) {
    if (threadIdx.x == 0) {
        int co = 0, go = 0;
        for (int k = 0; k < 27; ++k) {
            hdr[32 + k] = co; hdr[64 + k] = go;
            int nch = (hdr[k] + 31) / 32;
            co += nch; go += nch * 32;
        }
        hdr[32 + 27] = co;
    }
}

// ---------------------------------------------------------------------------
// convB: persistent per-tap dense GEMM over compacted 32-row chunks.
// g[goff[k] + row] = bf16( x[pairs[k][row]] @ W[k] )
// ---------------------------------------------------------------------------
__global__ __launch_bounds__(256) void convB(const float* __restrict__ x, const int* __restrict__ pairs,
                                             const int* __restrict__ hdr, const bfx8* __restrict__ Wf,
                                             unsigned short* __restrict__ g) {
    const int tid = threadIdx.x, l = tid & 63, w = tid >> 6, rr = tid >> 4, gg = tid & 15;
    __shared__ int sco[28], scnt[27], sgo[27];
    __shared__ unsigned short Ash[32 * AROW];
    __shared__ unsigned short Osh[32 * AROW];
    if (tid < 28) sco[tid] = hdr[32 + tid];
    if (tid < 27) { scnt[tid] = hdr[tid]; sgo[tid] = hdr[64 + tid]; }
    __syncthreads();
    const int tot = sco[27];
    for (int t = blockIdx.x; t < tot; t += gridDim.x) {
        int lo = 0, hi = 26;
        while (lo < hi) { int mid = (lo + hi + 1) >> 1; if (sco[mid] <= t) lo = mid; else hi = mid - 1; }
        const int k = lo, c = t - sco[k], cntk = scnt[k];
        const int srow = c * 32;
        const size_t gbase = (size_t)(sgo[k] + srow) * C;
#pragma unroll
        for (int h = 0; h < 2; ++h) {
            int row = srow + h * 16 + rr;
            uint4 pk = {0u, 0u, 0u, 0u};
            if (row < cntk) {
                int j = pairs[(size_t)k * NN + row];
                const float* xr = x + (size_t)j * C + gg * 8;
                float4 xa = *reinterpret_cast<const float4*>(xr);
                float4 xb = *reinterpret_cast<const float4*>(xr + 4);
                pk.x = pack_bf2(xa.x, xa.y); pk.y = pack_bf2(xa.z, xa.w);
                pk.z = pack_bf2(xb.x, xb.y); pk.w = pack_bf2(xb.z, xb.w);
            }
            *reinterpret_cast<uint4*>(&Ash[(h * 16 + rr) * AROW + gg * 8]) = pk;
        }
        __syncthreads();
        f32x4 a00 = {0.f,0.f,0.f,0.f}, a01 = {0.f,0.f,0.f,0.f};
        f32x4 a10 = {0.f,0.f,0.f,0.f}, a11 = {0.f,0.f,0.f,0.f};
        const unsigned short* ar0 = &Ash[(l & 15) * AROW + (l >> 4) * 8];
        const unsigned short* ar1 = &Ash[(16 + (l & 15)) * AROW + (l >> 4) * 8];
#pragma unroll
        for (int ks = 0; ks < 4; ++ks) {
            bfx8 b0 = Wf[((k * 4 + ks) * 8 + 2 * w) * 64 + l];
            bfx8 b1 = Wf[((k * 4 + ks) * 8 + 2 * w + 1) * 64 + l];
            bfx8 f0 = *reinterpret_cast<const bfx8*>(ar0 + ks * 32);
            bfx8 f1 = *reinterpret_cast<const bfx8*>(ar1 + ks * 32);
            a00 = __builtin_amdgcn_mfma_f32_16x16x32_bf16(f0, b0, a00, 0, 0, 0);
            a01 = __builtin_amdgcn_mfma_f32_16x16x32_bf16(f0, b1, a01, 0, 0, 0);
            a10 = __builtin_amdgcn_mfma_f32_16x16x32_bf16(f1, b0, a10, 0, 0, 0);
            a11 = __builtin_amdgcn_mfma_f32_16x16x32_bf16(f1, b1, a11, 0, 0, 0);
        }
#pragma unroll
        for (int r = 0; r < 4; ++r) {
            int row = (l >> 4) * 4 + r;
            Osh[row * AROW + w * 32 + (l & 15)]        = bf1(a00[r]);
            Osh[row * AROW + w * 32 + 16 + (l & 15)]   = bf1(a01[r]);
            Osh[(16 + row) * AROW + w * 32 + (l & 15)] = bf1(a10[r]);
            Osh[(16 + row) * AROW + w * 32 + 16 + (l & 15)] = bf1(a11[r]);
        }
        __syncthreads();
#pragma unroll
        for (int h = 0; h < 2; ++h) {
            int row = h * 16 + rr;
            uint4 v = *reinterpret_cast<uint4*>(&Osh[row * AROW + gg * 8]);
            *reinterpret_cast<uint4*>(&g[gbase + (size_t)row * C + gg * 8]) = v;
        }
        __syncthreads();
    }
}

// ---------------------------------------------------------------------------
// convC: out[i] = sum over valid taps k of g[goff[k]+slotmap[k][i]].
// Per-point bitmask -> only ~2.24 gathers/point. Fused BN partial stats.
// ---------------------------------------------------------------------------
__global__ __launch_bounds__(256) void convC(const unsigned short* __restrict__ g, const int* __restrict__ slotmap,
                                             const int* __restrict__ hdr, const unsigned* __restrict__ maskbuf,
                                             float* __restrict__ out, float* __restrict__ psb,
                                             float* __restrict__ pqb) {
    const int tid = threadIdx.x, p = tid >> 4, gg = tid & 15, c0 = gg * 8;
    const int i = blockIdx.x * 16 + p;
    __shared__ int sgo[27];
    __shared__ float outt[16 * 132];
    if (tid < 27) sgo[tid] = hdr[64 + tid];
    __syncthreads();
    unsigned m = maskbuf[i];
    float acc[8] = {0.f,0.f,0.f,0.f,0.f,0.f,0.f,0.f};
    while (m) {
        int k = (int)__builtin_ctz(m); m &= m - 1;
        int slot = slotmap[(size_t)k * NN + i];
        const unsigned short* gr = &g[(size_t)(sgo[k] + slot) * C + c0];
        uint4 u = *reinterpret_cast<const uint4*>(gr);
        acc[0] += __uint_as_float(u.x << 16); acc[1] += __uint_as_float(u.x & 0xffff0000u);
        acc[2] += __uint_as_float(u.y << 16); acc[3] += __uint_as_float(u.y & 0xffff0000u);
        acc[4] += __uint_as_float(u.z << 16); acc[5] += __uint_as_float(u.z & 0xffff0000u);
        acc[6] += __uint_as_float(u.w << 16); acc[7] += __uint_as_float(u.w & 0xffff0000u);
    }
#pragma unroll
    for (int c2 = 0; c2 < 8; ++c2) outt[p * 132 + c0 + c2] = acc[c2];
    float4 o0 = {acc[0], acc[1], acc[2], acc[3]};
    float4 o1 = {acc[4], acc[5], acc[6], acc[7]};
    float* op = out + (size_t)i * C + c0;
    *reinterpret_cast<float4*>(op) = o0;
    *reinterpret_cast<float4*>(op + 4) = o1;
    __syncthreads();
    if (tid < 128) {
        float s = 0.f, q = 0.f;
#pragma unroll
        for (int r = 0; r < 16; ++r) { float v = outt[r * 132 + tid]; s += v; q += v * v; }
        psb[(size_t)blockIdx.x * C + tid] = s;
        pqb[(size_t)blockIdx.x * C + tid] = q;
    }
}

// ---------------------------------------------------------------------------
// Dense [N,128]@[128,128] MFMA matmul, optional fused input BN+ReLU,
// fused per-block BN partial stats on the OUTPUT.
// ---------------------------------------------------------------------------
__global__ __launch_bounds__(256) void mm_bn_mfma(const float* __restrict__ in,
                                                  const float* __restrict__ a,
                                                  const float* __restrict__ cc,
                                                  int dorelu,
                                                  const bfx8* __restrict__ Wf,
                                                  float* __restrict__ out,
                                                  float* __restrict__ psb,
                                                  float* __restrict__ pqb) {
    const int tid = threadIdx.x, l = tid & 63, w = tid >> 6;
    const int rr = tid >> 4, gg = tid & 15;
    const size_t base = (size_t)blockIdx.x * 16;
    __shared__ unsigned short Ash[16 * AROW];
    __shared__ float outt[16 * 132];
    {
        const float* xr = in + (base + rr) * C + gg * 8;
        float4 xa = *reinterpret_cast<const float4*>(xr);
        float4 xb = *reinterpret_cast<const float4*>(xr + 4);
        if (dorelu) {
            float4 a4 = *reinterpret_cast<const float4*>(&a[gg * 8]);
            float4 a4b = *reinterpret_cast<const float4*>(&a[gg * 8 + 4]);
            float4 c4 = *reinterpret_cast<const float4*>(&cc[gg * 8]);
            float4 c4b = *reinterpret_cast<const float4*>(&cc[gg * 8 + 4]);
            xa.x = fmaxf(fmaf(xa.x, a4.x, c4.x), 0.f);
            xa.y = fmaxf(fmaf(xa.y, a4.y, c4.y), 0.f);
            xa.z = fmaxf(fmaf(xa.z, a4.z, c4.z), 0.f);
            xa.w = fmaxf(fmaf(xa.w, a4.w, c4.w), 0.f);
            xb.x = fmaxf(fmaf(xb.x, a4b.x, c4b.x), 0.f);
            xb.y = fmaxf(fmaf(xb.y, a4b.y, c4b.y), 0.f);
            xb.z = fmaxf(fmaf(xb.z, a4b.z, c4b.z), 0.f);
            xb.w = fmaxf(fmaf(xb.w, a4b.w, c4b.w), 0.f);
        }
        uint4 pk;
        pk.x = pack_bf2(xa.x, xa.y); pk.y = pack_bf2(xa.z, xa.w);
        pk.z = pack_bf2(xb.x, xb.y); pk.w = pack_bf2(xb.z, xb.w);
        *reinterpret_cast<uint4*>(&Ash[rr * AROW + gg * 8]) = pk;
    }
    __syncthreads();
    f32x4 acc0 = {0.f, 0.f, 0.f, 0.f};
    f32x4 acc1 = {0.f, 0.f, 0.f, 0.f};
    const unsigned short* arow = &Ash[(l & 15) * AROW + (l >> 4) * 8];
#pragma unroll
    for (int ks = 0; ks < 4; ++ks) {
        bfx8 af = *reinterpret_cast<const bfx8*>(arow + ks * 32);
        bfx8 b0 = Wf[(ks * 8 + 2 * w) * 64 + l];
        bfx8 b1 = Wf[(ks * 8 + 2 * w + 1) * 64 + l];
        acc0 = __builtin_amdgcn_mfma_f32_16x16x32_bf16(af, b0, acc0, 0, 0, 0);
        acc1 = __builtin_amdgcn_mfma_f32_16x16x32_bf16(af, b1, acc1, 0, 0, 0);
    }
#pragma unroll
    for (int r = 0; r < 4; ++r) {
        int row = (l >> 4) * 4 + r;
        outt[row * 132 + w * 32 + (l & 15)] = acc0[r];
        outt[row * 132 + w * 32 + 16 + (l & 15)] = acc1[r];
    }
    __syncthreads();
    {
        float4 v0 = *reinterpret_cast<float4*>(&outt[rr * 132 + gg * 8]);
        float4 v1 = *reinterpret_cast<float4*>(&outt[rr * 132 + gg * 8 + 4]);
        float* op = out + (base + rr) * C + gg * 8;
        *reinterpret_cast<float4*>(op) = v0;
        *reinterpret_cast<float4*>(op + 4) = v1;
    }
    if (tid < 128) {
        float s = 0.f, q = 0.f;
#pragma unroll
        for (int r = 0; r < 16; ++r) { float v = outt[r * 132 + tid]; s += v; q += v * v; }
        psb[(size_t)blockIdx.x * C + tid] = s;
        pqb[(size_t)blockIdx.x * C + tid] = q;
    }
}

// ---------------------------------------------------------------------------
// q = x @ q_w  ([N,128] @ [128,16])
// ---------------------------------------------------------------------------
__global__ __launch_bounds__(256) void qmm(const float* __restrict__ x,
                                           const float* __restrict__ qw,
                                           float* __restrict__ outq) {
    const int v = threadIdx.x & 15, p = threadIdx.x >> 4;
    const size_t i = (size_t)blockIdx.x * 16 + p;
    float acc = 0.f;
    for (int cin0 = 0; cin0 < C; cin0 += 4) {
        float4 xv = *reinterpret_cast<const float4*>(x + i * C + cin0);
        acc += xv.x * qw[(cin0 + 0) * VEC + v] + xv.y * qw[(cin0 + 1) * VEC + v]
             + xv.z * qw[(cin0 + 2) * VEC + v] + xv.w * qw[(cin0 + 3) * VEC + v];
    }
    outq[i * VEC + v] = acc;
}

// ---------------------------------------------------------------------------
// Reductions
// ---------------------------------------------------------------------------
__global__ __launch_bounds__(256) void stats_mid128(const float* __restrict__ psb,
                                                    const float* __restrict__ pqb,
                                                    int rows,
                                                    float* __restrict__ ps2,
                                                    float* __restrict__ pq2) {
    const int ch = threadIdx.x & 127, half = threadIdx.x >> 7;
    float s = 0.f, q = 0.f;
    for (int i = blockIdx.x * 2 + half; i < rows; i += 128) {
        s += psb[(size_t)i * C + ch];
        q += pqb[(size_t)i * C + ch];
    }
    __shared__ float ls[256], lq[256];
    ls[threadIdx.x] = s; lq[threadIdx.x] = q;
    __syncthreads();
    if (threadIdx.x < 128) {
        ps2[blockIdx.x * C + ch] = ls[threadIdx.x] + ls[threadIdx.x + 128];
        pq2[blockIdx.x * C + ch] = lq[threadIdx.x] + lq[threadIdx.x + 128];
    }
}

__global__ __launch_bounds__(256) void stats_partial16(const float* __restrict__ buf,
                                                       float* __restrict__ ps,
                                                       float* __restrict__ pq) {
    const int ch = threadIdx.x & 15, grp = threadIdx.x >> 4;
    float s = 0.f, q = 0.f;
    for (int i = blockIdx.x * 16 + grp; i < NN; i += gridDim.x * 16) {
        float val = buf[(size_t)i * VEC + ch];
        s += val; q += val * val;
    }
    __shared__ float ls[256], lq[256];
    ls[threadIdx.x] = s; lq[threadIdx.x] = q;
    __syncthreads();
    if (threadIdx.x < 16) {
        float ss = 0.f, qq = 0.f;
        for (int g2 = 0; g2 < 16; ++g2) { ss += ls[g2 * 16 + ch]; qq += lq[g2 * 16 + ch]; }
        ps[blockIdx.x * VEC + ch] = ss; pq[blockIdx.x * VEC + ch] = qq;
    }
}

__global__ void stats_final(const float* __restrict__ ps, const float* __restrict__ pq,
                            int nb, int cdim,
                            const float* __restrict__ g, const float* __restrict__ b,
                            float* __restrict__ a, float* __restrict__ cc) {
    int ch = threadIdx.x;
    if (ch >= cdim) return;
    float s = 0.f, q = 0.f;
    for (int i = 0; i < nb; ++i) { s += ps[i * cdim + ch]; q += pq[i * cdim + ch]; }
    float m = s / (float)NN;
    float var = q / (float)NN - m * m;
    var = fmaxf(var, 0.f);
    float rs = rsqrtf(var + 1e-5f);
    float av = g[ch] * rs;
    a[ch] = av;
    cc[ch] = b[ch] - m * av;
}

// in-place y = relu(y*a[ch] + c[ch]); mask = channel mask (pow2-1)
__global__ __launch_bounds__(256) void bn_relu_ip(float* __restrict__ buf,
                                                  const float* __restrict__ a,
                                                  const float* __restrict__ cc,
                                                  int total4, int mask) {
    for (int t = blockIdx.x * blockDim.x + threadIdx.x; t < total4; t += gridDim.x * blockDim.x) {
        float4 v = reinterpret_cast<float4*>(buf)[t];
        int ch = (t * 4) & mask;
        v.x = fmaxf(fmaf(v.x, a[ch + 0], cc[ch + 0]), 0.f);
        v.y = fmaxf(fmaf(v.y, a[ch + 1], cc[ch + 1]), 0.f);
        v.z = fmaxf(fmaf(v.z, a[ch + 2], cc[ch + 2]), 0.f);
        v.w = fmaxf(fmaf(v.w, a[ch + 3], cc[ch + 3]), 0.f);
        reinterpret_cast<float4*>(buf)[t] = v;
    }
}

// BN+ReLU applied, output bf16 (v buffer for the attention stage)
__global__ __launch_bounds__(256) void bnrelu_bf16(const float* __restrict__ in,
                                                   const float* __restrict__ a,
                                                   const float* __restrict__ cc,
                                                   unsigned short* __restrict__ outh) {
    const int total8 = NN * C / 8;
    for (int t = blockIdx.x * 256 + threadIdx.x; t < total8; t += gridDim.x * 256) {
        int ch = (t * 8) & 127;
        const float* xr = in + (size_t)t * 8;
        float4 xa = *reinterpret_cast<const float4*>(xr);
        float4 xb = *reinterpret_cast<const float4*>(xr + 4);
        float4 a4 = *reinterpret_cast<const float4*>(&a[ch]);
        float4 a4b = *reinterpret_cast<const float4*>(&a[ch + 4]);
        float4 c4 = *reinterpret_cast<const float4*>(&cc[ch]);
        float4 c4b = *reinterpret_cast<const float4*>(&cc[ch + 4]);
        xa.x = fmaxf(fmaf(xa.x, a4.x, c4.x), 0.f);
        xa.y = fmaxf(fmaf(xa.y, a4.y, c4.y), 0.f);
        xa.z = fmaxf(fmaf(xa.z, a4.z, c4.z), 0.f);
        xa.w = fmaxf(fmaf(xa.w, a4.w, c4.w), 0.f);
        xb.x = fmaxf(fmaf(xb.x, a4b.x, c4b.x), 0.f);
        xb.y = fmaxf(fmaf(xb.y, a4b.y, c4b.y), 0.f);
        xb.z = fmaxf(fmaf(xb.z, a4b.z, c4b.z), 0.f);
        xb.w = fmaxf(fmaf(xb.w, a4b.w, c4b.w), 0.f);
        uint4 pk;
        pk.x = pack_bf2(xa.x, xa.y); pk.y = pack_bf2(xa.z, xa.w);
        pk.z = pack_bf2(xb.x, xb.y); pk.w = pack_bf2(xb.z, xb.w);
        *reinterpret_cast<uint4*>(&outh[(size_t)t * 8]) = pk;
    }
}

// ---------------------------------------------------------------------------
// Fused attention: 16 points / 256-thread block, zero-row trick (index NN
// = zero row), 8 channels/thread via uint4 bf16 loads. No mask arithmetic.
// ---------------------------------------------------------------------------
__global__ __launch_bounds__(256) void attn_fused16(const unsigned short* __restrict__ vbf,
                                                    const float* __restrict__ qbuf,
                                                    const int* __restrict__ nA,
                                                    const int* __restrict__ nB,
                                                    const int* __restrict__ nC,
                                                    const float* __restrict__ cb0,
                                                    const float* __restrict__ cb1,
                                                    const float* __restrict__ cb2,
                                                    float* __restrict__ outm) {
    const int tid = threadIdx.x;
    const int base = blockIdx.x * 16;
    __shared__ int sidx[16][48];
    __shared__ float scnt[16][3];
    __shared__ float sattn[16][16][3];

    for (int t = tid; t < 656; t += 256) {
        int k = t >> 4, p = t & 15;
        int i = base + p;
        int j;
        if (k < 7)       j = nA[(size_t)k * NN + i];
        else if (k < 34) j = nB[(size_t)(k - 7) * NN + i];
        else             j = nC[(size_t)(k - 34) * NN + i];
        sidx[p][k] = (j >= 0) ? j : NN;
    }
    __syncthreads();
    if (tid < 48) {
        int p = tid & 15, e = tid >> 4;
        int k0 = (e == 0) ? 0 : ((e == 1) ? 7 : 34);
        int k1 = (e == 0) ? 7 : ((e == 1) ? 34 : 41);
        int cnt = 0;
        for (int k = k0; k < k1; ++k) cnt += (sidx[p][k] != NN);
        scnt[p][e] = (float)(cnt > 0 ? cnt : 1);
    }
    __syncthreads();
    {
        int p = tid >> 4, v = tid & 15;
        float qi = qbuf[(size_t)(base + p) * VEC + v];
        float a0 = 0.f, a1 = 0.f, a2 = 0.f;
#pragma unroll
        for (int k = 0; k < 7; ++k)  a0 += qbuf[(size_t)sidx[p][k] * VEC + v];
#pragma unroll 9
        for (int k = 7; k < 34; ++k) a1 += qbuf[(size_t)sidx[p][k] * VEC + v];
#pragma unroll
        for (int k = 34; k < 41; ++k) a2 += qbuf[(size_t)sidx[p][k] * VEC + v];
        float s0 = qi * a0 / scnt[p][0];
        float s1 = qi * a1 / scnt[p][1];
        float s2 = qi * a2 / scnt[p][2];
        float mx = fmaxf(s0, fmaxf(s1, s2));
        float e0 = __expf(s0 - mx), e1 = __expf(s1 - mx), e2 = __expf(s2 - mx);
        float inv = 1.f / (e0 + e1 + e2);
        sattn[p][v][0] = e0 * inv; sattn[p][v][1] = e1 * inv; sattn[p][v][2] = e2 * inv;
    }
    __syncthreads();
    {
        int p = tid >> 4, g = tid & 15, c0 = g * 8;
        float A0[8], A1[8], A2[8];
#pragma unroll
        for (int c = 0; c < 8; ++c) { A0[c] = 0.f; A1[c] = 0.f; A2[c] = 0.f; }
#pragma unroll
        for (int k = 0; k < 7; ++k) {
            int jc = sidx[p][k];
            uint4 u = *reinterpret_cast<const uint4*>(vbf + (size_t)jc * C + c0);
            float4 ca = *reinterpret_cast<const float4*>(&cb0[k * C + c0]);
            float4 cb = *reinterpret_cast<const float4*>(&cb0[k * C + c0 + 4]);
            A0[0] = fmaf(ca.x, __uint_as_float(u.x << 16), A0[0]);
            A0[1] = fmaf(ca.y, __uint_as_float(u.x & 0xffff0000u), A0[1]);
            A0[2] = fmaf(ca.z, __uint_as_float(u.y << 16), A0[2]);
            A0[3] = fmaf(ca.w, __uint_as_float(u.y & 0xffff0000u), A0[3]);
            A0[4] = fmaf(cb.x, __uint_as_float(u.z << 16), A0[4]);
            A0[5] = fmaf(cb.y, __uint_as_float(u.z & 0xffff0000u), A0[5]);
            A0[6] = fmaf(cb.z, __uint_as_float(u.w << 16), A0[6]);
            A0[7] = fmaf(cb.w, __uint_as_float(u.w & 0xffff0000u), A0[7]);
        }
#pragma unroll 9
        for (int k = 7; k < 34; ++k) {
            int jc = sidx[p][k];
            uint4 u = *reinterpret_cast<const uint4*>(vbf + (size_t)jc * C + c0);
            float4 ca = *reinterpret_cast<const float4*>(&cb1[(k - 7) * C + c0]);
            float4 cb = *reinterpret_cast<const float4*>(&cb1[(k - 7) * C + c0 + 4]);
            A1[0] = fmaf(ca.x, __uint_as_float(u.x << 16), A1[0]);
            A1[1] = fmaf(ca.y, __uint_as_float(u.x & 0xffff0000u), A1[1]);
            A1[2] = fmaf(ca.z, __uint_as_float(u.y << 16), A1[2]);
            A1[3] = fmaf(ca.w, __uint_as_float(u.y & 0xffff0000u), A1[3]);
            A1[4] = fmaf(cb.x, __uint_as_float(u.z << 16), A1[4]);
            A1[5] = fmaf(cb.y, __uint_as_float(u.z & 0xffff0000u), A1[5]);
            A1[6] = fmaf(cb.z, __uint_as_float(u.w << 16), A1[6]);
            A1[7] = fmaf(cb.w, __uint_as_float(u.w & 0xffff0000u), A1[7]);
        }
#pragma unroll
        for (int k = 34; k < 41; ++k) {
            int jc = sidx[p][k];
            uint4 u = *reinterpret_cast<const uint4*>(vbf + (size_t)jc * C + c0);
            float4 ca = *reinterpret_cast<const float4*>(&cb2[(k - 34) * C + c0]);
            float4 cb = *reinterpret_cast<const float4*>(&cb2[(k - 34) * C + c0 + 4]);
            A2[0] = fmaf(ca.x, __uint_as_float(u.x << 16), A2[0]);
            A2[1] = fmaf(ca.y, __uint_as_float(u.x & 0xffff0000u), A2[1]);
            A2[2] = fmaf(ca.z, __uint_as_float(u.y << 16), A2[2]);
            A2[3] = fmaf(ca.w, __uint_as_float(u.y & 0xffff0000u), A2[3]);
            A2[4] = fmaf(cb.x, __uint_as_float(u.z << 16), A2[4]);
            A2[5] = fmaf(cb.y, __uint_as_float(u.z & 0xffff0000u), A2[5]);
            A2[6] = fmaf(cb.z, __uint_as_float(u.w << 16), A2[6]);
            A2[7] = fmaf(cb.w, __uint_as_float(u.w & 0xffff0000u), A2[7]);
        }
        float w0 = sattn[p][g][0], w1 = sattn[p][g][1], w2 = sattn[p][g][2];
        float o[8];
#pragma unroll
        for (int c = 0; c < 8; ++c) o[c] = w0 * A0[c] + w1 * A1[c] + w2 * A2[c];
        float* op = &outm[(size_t)(base + p) * C + c0];
        float4 o0 = {o[0], o[1], o[2], o[3]};
        float4 o1 = {o[4], o[5], o[6], o[7]};
        *reinterpret_cast<float4*>(op) = o0;
        *reinterpret_cast<float4*>(op + 4) = o1;
    }
}

// out = relu(buf*a + c) + x
__global__ __launch_bounds__(256) void final_bn_res(const float* __restrict__ buf,
                                                    const float* __restrict__ a,
                                                    const float* __restrict__ cc,
                                                    const float* __restrict__ x,
                                                    float* __restrict__ out, int total4) {
    for (int t = blockIdx.x * blockDim.x + threadIdx.x; t < total4; t += gridDim.x * blockDim.x) {
        float4 v = reinterpret_cast<const float4*>(buf)[t];
        float4 xv = reinterpret_cast<const float4*>(x)[t];
        int ch = (t * 4) & 127;
        v.x = fmaxf(fmaf(v.x, a[ch + 0], cc[ch + 0]), 0.f) + xv.x;
        v.y = fmaxf(fmaf(v.y, a[ch + 1], cc[ch + 1]), 0.f) + xv.y;
        v.z = fmaxf(fmaf(v.z, a[ch + 2], cc[ch + 2]), 0.f) + xv.z;
        v.w = fmaxf(fmaf(v.w, a[ch + 3], cc[ch + 3]), 0.f) + xv.w;
        reinterpret_cast<float4*>(out)[t] = v;
    }
}

extern "C" void kernel_launch(void* const* d_in, const int* in_sizes, int n_in,
                              void* d_out, int out_size, void* d_ws, size_t ws_size,
                              hipStream_t stream) {
    (void)in_sizes; (void)n_in; (void)out_size; (void)ws_size;
    const float* x    = (const float*)d_in[0];
    const float* v1_w = (const float*)d_in[1];
    const float* v1_g = (const float*)d_in[2];
    const float* v1_b = (const float*)d_in[3];
    const float* v2_w = (const float*)d_in[4];
    const float* v2_g = (const float*)d_in[5];
    const float* v2_b = (const float*)d_in[6];
    const float* q_w  = (const float*)d_in[7];
    const float* q_g  = (const float*)d_in[8];
    const float* q_b  = (const float*)d_in[9];
    const float* cb0  = (const float*)d_in[10];
    const float* cb1  = (const float*)d_in[11];
    const float* cb2  = (const float*)d_in[12];
    const float* out_w = (const float*)d_in[13];
    const float* out_g = (const float*)d_in[14];
    const float* out_b = (const float*)d_in[15];
    const int* nbrA = (const int*)d_in[16];   // cross2, K=7
    const int* nbrB = (const int*)d_in[17];   // cube,  K=27
    const int* nbrC = (const int*)d_in[18];   // cross3, K=7
    float* out = (float*)d_out;

    float* w = (float*)d_ws;
    // region0: bufA (conv1 / attn output)
    float* bufA = w;                               // NN*C = 12,800,000 floats
    // region1: conv-stage {g, slotmap, pairs} ALIASES later-stage {bufB, bufQ, vbf}
    float* r1 = w + (size_t)NN * C;
    float* bufB = r1;                              // NN*C floats
    float* bufQ = r1 + (size_t)NN * C;             // (NN+1)*VEC floats (zero row at NN)
    unsigned short* vbf = (unsigned short*)(r1 + (size_t)NN * C + (size_t)(NN + 1) * VEC); // (NN+1)*C ushorts
    unsigned short* g = (unsigned short*)r1;       // GCAP*C ushorts = 15,360,000 floats
    int* slotmap = (int*)(r1 + 15360000);          // 27*NN = 2,700,000 ints
    int* pairs   = (int*)(r1 + 15360000 + 2700000);// 27*NN ints
    size_t o = (size_t)NN * C + 20810000;          // end of region1
    float* psb  = w + o; o += (size_t)6250 * C;
    float* pqb  = w + o; o += (size_t)6250 * C;
    float* ps2  = w + o; o += 64 * C;
    float* pq2  = w + o; o += 64 * C;
    float* ps16 = w + o; o += 128 * VEC;
    float* pq16 = w + o; o += 128 * VEC;
    float* a1 = w + o; o += C;  float* c1 = w + o; o += C;
    float* a2 = w + o; o += C;  float* c2 = w + o; o += C;
    float* ao = w + o; o += C;  float* co = w + o; o += C;
    float* aq = w + o; o += VEC; float* cq = w + o; o += VEC;
    unsigned short* v1f = (unsigned short*)(w + o); o += (27 * 16384) / 2;
    unsigned short* v2f = (unsigned short*)(w + o); o += 16384 / 2;
    unsigned short* outf = (unsigned short*)(w + o); o += 16384 / 2;
    int* hdr = (int*)(w + o); o += 128;
    unsigned* maskbuf = (unsigned*)(w + o); o += NN;

    const int total4  = NN * C / 4;
    const int total4q = NN * VEC / 4;

    hipMemsetAsync(hdr, 0, (size_t)(128 + NN) * sizeof(int), stream);
    prep<<<1857, 256, 0, stream>>>(v1_w, v2_w, out_w, v1f, v2f, outf,
                                   bufQ + (size_t)NN * VEC, vbf + (size_t)NN * C);

    // conv1 (cube-27) via per-tap compaction + dense GEMM + scatter-sum
    compactA<<<27 * 49, 256, 0, stream>>>(nbrB, hdr, slotmap, pairs, maskbuf);
    prefixA2<<<1, 64, 0, stream>>>(hdr);
    convB<<<2048, 256, 0, stream>>>(x, pairs, hdr, (const bfx8*)v1f, g);
    convC<<<NN / 16, 256, 0, stream>>>(g, slotmap, hdr, maskbuf, bufA, psb, pqb);
    stats_mid128<<<64, 256, 0, stream>>>(psb, pqb, 6250, ps2, pq2);
    stats_final<<<1, 128, 0, stream>>>(ps2, pq2, 64, C, v1_g, v1_b, a1, c1);

    // v2 1x1 conv with fused input BN+ReLU -> bufB (g is dead now), fused stats
    mm_bn_mfma<<<NN / 16, 256, 0, stream>>>(bufA, a1, c1, 1, (const bfx8*)v2f, bufB, psb, pqb);
    stats_mid128<<<64, 256, 0, stream>>>(psb, pqb, 6250, ps2, pq2);
    stats_final<<<1, 128, 0, stream>>>(ps2, pq2, 64, C, v2_g, v2_b, a2, c2);

    // v = relu(bn(bufB)) as bf16
    bnrelu_bf16<<<2048, 256, 0, stream>>>(bufB, a2, c2, vbf);

    // query branch
    qmm<<<NN / 16, 256, 0, stream>>>(x, q_w, bufQ);
    stats_partial16<<<128, 256, 0, stream>>>(bufQ, ps16, pq16);
    stats_final<<<1, 64, 0, stream>>>(ps16, pq16, 128, VEC, q_g, q_b, aq, cq);
    bn_relu_ip<<<1024, 256, 0, stream>>>(bufQ, aq, cq, total4q, 15);

    // fused expert convs + attention mix -> bufA
    attn_fused16<<<NN / 16, 256, 0, stream>>>(vbf, bufQ, nbrA, nbrB, nbrC, cb0, cb1, cb2, bufA);

    // output 1x1 conv -> bufB, fused stats; final residual
    mm_bn_mfma<<<NN / 16, 256, 0, stream>>>(bufA, nullptr, nullptr, 0, (const bfx8*)outf, bufB, psb, pqb);
    stats_mid128<<<64, 256, 0, stream>>>(psb, pqb, 6250, ps2, pq2);
    stats_final<<<1, 128, 0, stream>>>(ps2, pq2, 64, C, out_g, out_b, ao, co);
    final_bn_res<<<2048, 256, 0, stream>>>(bufB, ao, co, x, out, total4);
}

// Round 6
// 389.935 us; speedup vs baseline: 5.9366x; 1.3131x over previous
//
#include <hip/hip_runtime.h>

#define NN 100000
#define C 128
#define VEC 16
#define AROW 136   // padded LDS row stride (ushorts)
#define GCAP 240000

typedef __bf16 bfx8 __attribute__((ext_vector_type(8)));
typedef float f32x4 __attribute__((ext_vector_type(4)));

__device__ inline unsigned pack_bf2(float a, float b) {
    unsigned ua = __float_as_uint(a);
    unsigned ub = __float_as_uint(b);
    ua = (ua + 0x7fffu + ((ua >> 16) & 1u)) >> 16;
    ub = (ub + 0x7fffu + ((ub >> 16) & 1u)) >> 16;
    return ua | (ub << 16);
}
__device__ inline unsigned short bf1(float a) {
    unsigned u = __float_as_uint(a);
    return (unsigned short)((u + 0x7fffu + ((u >> 16) & 1u)) >> 16);
}

// ---------------------------------------------------------------------------
// Prep: weight pre-swizzles (MFMA B-fragment bf16).
// Wf[(((kt*4+ks)*8+nt)*64+l)*8+e] = bf16(W[kt][ks*32+(l>>4)*8+e][nt*16+(l&15)])
// ---------------------------------------------------------------------------
__device__ inline void wconv_body(const float* __restrict__ W, unsigned short* __restrict__ Wf, int F) {
    int e = F & 7, l = (F >> 3) & 63, nt = (F >> 9) & 7, ks = (F >> 12) & 3, kt = F >> 14;
    int cin = ks * 32 + (l >> 4) * 8 + e;
    int cout = nt * 16 + (l & 15);
    Wf[F] = bf1(W[((size_t)kt * C + cin) * C + cout]);
}

__global__ __launch_bounds__(256) void prep(const float* __restrict__ v1w, const float* __restrict__ v2w,
                                            const float* __restrict__ outw,
                                            unsigned short* __restrict__ v1f, unsigned short* __restrict__ v2f,
                                            unsigned short* __restrict__ outf) {
    int b = blockIdx.x, tid = threadIdx.x;
    if (b < 1728)       wconv_body(v1w, v1f, b * 256 + tid);
    else if (b < 1792)  wconv_body(v2w, v2f, (b - 1728) * 256 + tid);
    else                wconv_body(outw, outf, (b - 1792) * 256 + tid);
}

// ---------------------------------------------------------------------------
// compactA: per-tap compacted pair lists (block = tap k x 2048-point chunk).
// ---------------------------------------------------------------------------
__global__ __launch_bounds__(256) void compactA(const int* __restrict__ nbr, int* __restrict__ cnt,
                                                int* __restrict__ slotmap, int* __restrict__ pairs,
                                                unsigned* __restrict__ maskbuf) {
    const int k = blockIdx.x / 49, cb = blockIdx.x % 49, tid = threadIdx.x;
    const int i0 = cb * 2048 + tid * 8;
    int j[8]; int lc = 0;
#pragma unroll
    for (int t = 0; t < 8; ++t) {
        int i = i0 + t;
        j[t] = (i < NN) ? nbr[(size_t)k * NN + i] : -1;
        lc += (j[t] >= 0);
    }
    __shared__ int ls[256]; __shared__ int sbase;
    ls[tid] = lc; __syncthreads();
    for (int off = 1; off < 256; off <<= 1) {
        int v = (tid >= off) ? ls[tid - off] : 0;
        __syncthreads();
        ls[tid] += v;
        __syncthreads();
    }
    if (tid == 255) sbase = atomicAdd(&cnt[k], ls[255]);
    __syncthreads();
    int slot = sbase + ls[tid] - lc;
    for (int t = 0; t < 8; ++t) {
        int i = i0 + t; if (i >= NN) break;
        int s = -1;
        if (j[t] >= 0) {
            s = slot++;
            pairs[(size_t)k * NN + s] = j[t];
            atomicOr(&maskbuf[i], 1u << k);
        }
        slotmap[(size_t)k * NN + i] = s;
    }
}

// hdr: [0..26]=cnt, [32..59]=chunkoff (28), [64..90]=goff (27)
__global__ void prefixA2(int* __restrict__ hdr) {
    if (threadIdx.x == 0) {
        int co = 0, go = 0;
        for (int k = 0; k < 27; ++k) {
            hdr[32 + k] = co; hdr[64 + k] = go;
            int nch = (hdr[k] + 31) / 32;
            co += nch; go += nch * 32;
        }
        hdr[32 + 27] = co;
    }
}

// ---------------------------------------------------------------------------
// convB: persistent per-tap dense GEMM over compacted 32-row chunks.
// ---------------------------------------------------------------------------
__global__ __launch_bounds__(256) void convB(const float* __restrict__ x, const int* __restrict__ pairs,
                                             const int* __restrict__ hdr, const bfx8* __restrict__ Wf,
                                             unsigned short* __restrict__ g) {
    const int tid = threadIdx.x, l = tid & 63, w = tid >> 6, rr = tid >> 4, gg = tid & 15;
    __shared__ int sco[28], scnt[27], sgo[27];
    __shared__ unsigned short Ash[32 * AROW];
    __shared__ unsigned short Osh[32 * AROW];
    if (tid < 28) sco[tid] = hdr[32 + tid];
    if (tid < 27) { scnt[tid] = hdr[tid]; sgo[tid] = hdr[64 + tid]; }
    __syncthreads();
    const int tot = sco[27];
    for (int t = blockIdx.x; t < tot; t += gridDim.x) {
        int lo = 0, hi = 26;
        while (lo < hi) { int mid = (lo + hi + 1) >> 1; if (sco[mid] <= t) lo = mid; else hi = mid - 1; }
        const int k = lo, c = t - sco[k], cntk = scnt[k];
        const int srow = c * 32;
        const size_t gbase = (size_t)(sgo[k] + srow) * C;
#pragma unroll
        for (int h = 0; h < 2; ++h) {
            int row = srow + h * 16 + rr;
            uint4 pk = {0u, 0u, 0u, 0u};
            if (row < cntk) {
                int j = pairs[(size_t)k * NN + row];
                const float* xr = x + (size_t)j * C + gg * 8;
                float4 xa = *reinterpret_cast<const float4*>(xr);
                float4 xb = *reinterpret_cast<const float4*>(xr + 4);
                pk.x = pack_bf2(xa.x, xa.y); pk.y = pack_bf2(xa.z, xa.w);
                pk.z = pack_bf2(xb.x, xb.y); pk.w = pack_bf2(xb.z, xb.w);
            }
            *reinterpret_cast<uint4*>(&Ash[(h * 16 + rr) * AROW + gg * 8]) = pk;
        }
        __syncthreads();
        f32x4 a00 = {0.f,0.f,0.f,0.f}, a01 = {0.f,0.f,0.f,0.f};
        f32x4 a10 = {0.f,0.f,0.f,0.f}, a11 = {0.f,0.f,0.f,0.f};
        const unsigned short* ar0 = &Ash[(l & 15) * AROW + (l >> 4) * 8];
        const unsigned short* ar1 = &Ash[(16 + (l & 15)) * AROW + (l >> 4) * 8];
#pragma unroll
        for (int ks = 0; ks < 4; ++ks) {
            bfx8 b0 = Wf[((k * 4 + ks) * 8 + 2 * w) * 64 + l];
            bfx8 b1 = Wf[((k * 4 + ks) * 8 + 2 * w + 1) * 64 + l];
            bfx8 f0 = *reinterpret_cast<const bfx8*>(ar0 + ks * 32);
            bfx8 f1 = *reinterpret_cast<const bfx8*>(ar1 + ks * 32);
            a00 = __builtin_amdgcn_mfma_f32_16x16x32_bf16(f0, b0, a00, 0, 0, 0);
            a01 = __builtin_amdgcn_mfma_f32_16x16x32_bf16(f0, b1, a01, 0, 0, 0);
            a10 = __builtin_amdgcn_mfma_f32_16x16x32_bf16(f1, b0, a10, 0, 0, 0);
            a11 = __builtin_amdgcn_mfma_f32_16x16x32_bf16(f1, b1, a11, 0, 0, 0);
        }
#pragma unroll
        for (int r = 0; r < 4; ++r) {
            int row = (l >> 4) * 4 + r;
            Osh[row * AROW + w * 32 + (l & 15)]        = bf1(a00[r]);
            Osh[row * AROW + w * 32 + 16 + (l & 15)]   = bf1(a01[r]);
            Osh[(16 + row) * AROW + w * 32 + (l & 15)] = bf1(a10[r]);
            Osh[(16 + row) * AROW + w * 32 + 16 + (l & 15)] = bf1(a11[r]);
        }
        __syncthreads();
#pragma unroll
        for (int h = 0; h < 2; ++h) {
            int row = h * 16 + rr;
            uint4 v = *reinterpret_cast<uint4*>(&Osh[row * AROW + gg * 8]);
            *reinterpret_cast<uint4*>(&g[gbase + (size_t)row * C + gg * 8]) = v;
        }
        __syncthreads();
    }
}

// ---------------------------------------------------------------------------
// convC: out[i] = sum over valid taps of g rows (bf16 out) + fused BN stats.
// ---------------------------------------------------------------------------
__global__ __launch_bounds__(256) void convC(const unsigned short* __restrict__ g, const int* __restrict__ slotmap,
                                             const int* __restrict__ hdr, const unsigned* __restrict__ maskbuf,
                                             unsigned short* __restrict__ outh, float* __restrict__ psb,
                                             float* __restrict__ pqb) {
    const int tid = threadIdx.x, p = tid >> 4, gg = tid & 15, c0 = gg * 8;
    const int i = blockIdx.x * 16 + p;
    __shared__ int sgo[27];
    __shared__ float outt[16 * 132];
    if (tid < 27) sgo[tid] = hdr[64 + tid];
    __syncthreads();
    unsigned m = maskbuf[i];
    float acc[8] = {0.f,0.f,0.f,0.f,0.f,0.f,0.f,0.f};
    while (m) {
        int k = (int)__builtin_ctz(m); m &= m - 1;
        int slot = slotmap[(size_t)k * NN + i];
        const unsigned short* gr = &g[(size_t)(sgo[k] + slot) * C + c0];
        uint4 u = *reinterpret_cast<const uint4*>(gr);
        acc[0] += __uint_as_float(u.x << 16); acc[1] += __uint_as_float(u.x & 0xffff0000u);
        acc[2] += __uint_as_float(u.y << 16); acc[3] += __uint_as_float(u.y & 0xffff0000u);
        acc[4] += __uint_as_float(u.z << 16); acc[5] += __uint_as_float(u.z & 0xffff0000u);
        acc[6] += __uint_as_float(u.w << 16); acc[7] += __uint_as_float(u.w & 0xffff0000u);
    }
#pragma unroll
    for (int c2 = 0; c2 < 8; ++c2) outt[p * 132 + c0 + c2] = acc[c2];
    uint4 pk;
    pk.x = pack_bf2(acc[0], acc[1]); pk.y = pack_bf2(acc[2], acc[3]);
    pk.z = pack_bf2(acc[4], acc[5]); pk.w = pack_bf2(acc[6], acc[7]);
    *reinterpret_cast<uint4*>(&outh[(size_t)i * C + c0]) = pk;
    __syncthreads();
    if (tid < 128) {
        float s = 0.f, q = 0.f;
#pragma unroll
        for (int r = 0; r < 16; ++r) { float v = outt[r * 132 + tid]; s += v; q += v * v; }
        psb[(size_t)blockIdx.x * C + tid] = s;
        pqb[(size_t)blockIdx.x * C + tid] = q;
    }
}

// ---------------------------------------------------------------------------
// Dense bf16[N,128]@[128,128] MFMA matmul, optional fused input BN+ReLU,
// bf16 output + fused fp32 BN partial stats on the output.
// ---------------------------------------------------------------------------
__global__ __launch_bounds__(256) void mm_bn_h(const unsigned short* __restrict__ in,
                                               const float* __restrict__ a,
                                               const float* __restrict__ cc,
                                               int dorelu,
                                               const bfx8* __restrict__ Wf,
                                               unsigned short* __restrict__ out,
                                               float* __restrict__ psb,
                                               float* __restrict__ pqb) {
    const int tid = threadIdx.x, l = tid & 63, w = tid >> 6;
    const int rr = tid >> 4, gg = tid & 15;
    const size_t base = (size_t)blockIdx.x * 16;
    __shared__ unsigned short Ash[16 * AROW];
    __shared__ float outt[16 * 132];
    {
        uint4 u = *reinterpret_cast<const uint4*>(in + (base + rr) * C + gg * 8);
        if (dorelu) {
            float4 a4 = *reinterpret_cast<const float4*>(&a[gg * 8]);
            float4 a4b = *reinterpret_cast<const float4*>(&a[gg * 8 + 4]);
            float4 c4 = *reinterpret_cast<const float4*>(&cc[gg * 8]);
            float4 c4b = *reinterpret_cast<const float4*>(&cc[gg * 8 + 4]);
            float e0 = fmaxf(fmaf(__uint_as_float(u.x << 16),        a4.x,  c4.x), 0.f);
            float e1 = fmaxf(fmaf(__uint_as_float(u.x & 0xffff0000u), a4.y,  c4.y), 0.f);
            float e2 = fmaxf(fmaf(__uint_as_float(u.y << 16),        a4.z,  c4.z), 0.f);
            float e3 = fmaxf(fmaf(__uint_as_float(u.y & 0xffff0000u), a4.w,  c4.w), 0.f);
            float e4 = fmaxf(fmaf(__uint_as_float(u.z << 16),        a4b.x, c4b.x), 0.f);
            float e5 = fmaxf(fmaf(__uint_as_float(u.z & 0xffff0000u), a4b.y, c4b.y), 0.f);
            float e6 = fmaxf(fmaf(__uint_as_float(u.w << 16),        a4b.z, c4b.z), 0.f);
            float e7 = fmaxf(fmaf(__uint_as_float(u.w & 0xffff0000u), a4b.w, c4b.w), 0.f);
            u.x = pack_bf2(e0, e1); u.y = pack_bf2(e2, e3);
            u.z = pack_bf2(e4, e5); u.w = pack_bf2(e6, e7);
        }
        *reinterpret_cast<uint4*>(&Ash[rr * AROW + gg * 8]) = u;
    }
    __syncthreads();
    f32x4 acc0 = {0.f, 0.f, 0.f, 0.f};
    f32x4 acc1 = {0.f, 0.f, 0.f, 0.f};
    const unsigned short* arow = &Ash[(l & 15) * AROW + (l >> 4) * 8];
#pragma unroll
    for (int ks = 0; ks < 4; ++ks) {
        bfx8 af = *reinterpret_cast<const bfx8*>(arow + ks * 32);
        bfx8 b0 = Wf[(ks * 8 + 2 * w) * 64 + l];
        bfx8 b1 = Wf[(ks * 8 + 2 * w + 1) * 64 + l];
        acc0 = __builtin_amdgcn_mfma_f32_16x16x32_bf16(af, b0, acc0, 0, 0, 0);
        acc1 = __builtin_amdgcn_mfma_f32_16x16x32_bf16(af, b1, acc1, 0, 0, 0);
    }
#pragma unroll
    for (int r = 0; r < 4; ++r) {
        int row = (l >> 4) * 4 + r;
        outt[row * 132 + w * 32 + (l & 15)] = acc0[r];
        outt[row * 132 + w * 32 + 16 + (l & 15)] = acc1[r];
    }
    __syncthreads();
    {
        float4 v0 = *reinterpret_cast<float4*>(&outt[rr * 132 + gg * 8]);
        float4 v1 = *reinterpret_cast<float4*>(&outt[rr * 132 + gg * 8 + 4]);
        uint4 pk;
        pk.x = pack_bf2(v0.x, v0.y); pk.y = pack_bf2(v0.z, v0.w);
        pk.z = pack_bf2(v1.x, v1.y); pk.w = pack_bf2(v1.z, v1.w);
        *reinterpret_cast<uint4*>(&out[(base + rr) * C + gg * 8]) = pk;
    }
    if (tid < 128) {
        float s = 0.f, q = 0.f;
#pragma unroll
        for (int r = 0; r < 16; ++r) { float v = outt[r * 132 + tid]; s += v; q += v * v; }
        psb[(size_t)blockIdx.x * C + tid] = s;
        pqb[(size_t)blockIdx.x * C + tid] = q;
    }
}

// ---------------------------------------------------------------------------
// q = x @ q_w  ([N,128] @ [128,16])
// ---------------------------------------------------------------------------
__global__ __launch_bounds__(256) void qmm(const float* __restrict__ x,
                                           const float* __restrict__ qw,
                                           float* __restrict__ outq) {
    const int v = threadIdx.x & 15, p = threadIdx.x >> 4;
    const size_t i = (size_t)blockIdx.x * 16 + p;
    float acc = 0.f;
    for (int cin0 = 0; cin0 < C; cin0 += 4) {
        float4 xv = *reinterpret_cast<const float4*>(x + i * C + cin0);
        acc += xv.x * qw[(cin0 + 0) * VEC + v] + xv.y * qw[(cin0 + 1) * VEC + v]
             + xv.z * qw[(cin0 + 2) * VEC + v] + xv.w * qw[(cin0 + 3) * VEC + v];
    }
    outq[i * VEC + v] = acc;
}

// ---------------------------------------------------------------------------
// Reductions
// ---------------------------------------------------------------------------
__global__ __launch_bounds__(256) void stats_mid128(const float* __restrict__ psb,
                                                    const float* __restrict__ pqb,
                                                    int rows,
                                                    float* __restrict__ ps2,
                                                    float* __restrict__ pq2) {
    const int ch = threadIdx.x & 127, half = threadIdx.x >> 7;
    float s = 0.f, q = 0.f;
    for (int i = blockIdx.x * 2 + half; i < rows; i += 128) {
        s += psb[(size_t)i * C + ch];
        q += pqb[(size_t)i * C + ch];
    }
    __shared__ float ls[256], lq[256];
    ls[threadIdx.x] = s; lq[threadIdx.x] = q;
    __syncthreads();
    if (threadIdx.x < 128) {
        ps2[blockIdx.x * C + ch] = ls[threadIdx.x] + ls[threadIdx.x + 128];
        pq2[blockIdx.x * C + ch] = lq[threadIdx.x] + lq[threadIdx.x + 128];
    }
}

__global__ __launch_bounds__(256) void stats_partial16(const float* __restrict__ buf,
                                                       float* __restrict__ ps,
                                                       float* __restrict__ pq) {
    const int ch = threadIdx.x & 15, grp = threadIdx.x >> 4;
    float s = 0.f, q = 0.f;
    for (int i = blockIdx.x * 16 + grp; i < NN; i += gridDim.x * 16) {
        float val = buf[(size_t)i * VEC + ch];
        s += val; q += val * val;
    }
    __shared__ float ls[256], lq[256];
    ls[threadIdx.x] = s; lq[threadIdx.x] = q;
    __syncthreads();
    if (threadIdx.x < 16) {
        float ss = 0.f, qq = 0.f;
        for (int g2 = 0; g2 < 16; ++g2) { ss += ls[g2 * 16 + ch]; qq += lq[g2 * 16 + ch]; }
        ps[blockIdx.x * VEC + ch] = ss; pq[blockIdx.x * VEC + ch] = qq;
    }
}

__global__ void stats_final(const float* __restrict__ ps, const float* __restrict__ pq,
                            int nb, int cdim,
                            const float* __restrict__ g, const float* __restrict__ b,
                            float* __restrict__ a, float* __restrict__ cc) {
    int ch = threadIdx.x;
    if (ch >= cdim) return;
    float s = 0.f, q = 0.f;
    for (int i = 0; i < nb; ++i) { s += ps[i * cdim + ch]; q += pq[i * cdim + ch]; }
    float m = s / (float)NN;
    float var = q / (float)NN - m * m;
    var = fmaxf(var, 0.f);
    float rs = rsqrtf(var + 1e-5f);
    float av = g[ch] * rs;
    a[ch] = av;
    cc[ch] = b[ch] - m * av;
}

// in-place y = relu(y*a[ch] + c[ch]); mask = channel mask (pow2-1)
__global__ __launch_bounds__(256) void bn_relu_ip(float* __restrict__ buf,
                                                  const float* __restrict__ a,
                                                  const float* __restrict__ cc,
                                                  int total4, int mask) {
    for (int t = blockIdx.x * blockDim.x + threadIdx.x; t < total4; t += gridDim.x * blockDim.x) {
        float4 v = reinterpret_cast<float4*>(buf)[t];
        int ch = (t * 4) & mask;
        v.x = fmaxf(fmaf(v.x, a[ch + 0], cc[ch + 0]), 0.f);
        v.y = fmaxf(fmaf(v.y, a[ch + 1], cc[ch + 1]), 0.f);
        v.z = fmaxf(fmaf(v.z, a[ch + 2], cc[ch + 2]), 0.f);
        v.w = fmaxf(fmaf(v.w, a[ch + 3], cc[ch + 3]), 0.f);
        reinterpret_cast<float4*>(buf)[t] = v;
    }
}

// BN+ReLU on bf16 input, bf16 output (v buffer for the attention stage)
__global__ __launch_bounds__(256) void bnrelu_h(const unsigned short* __restrict__ in,
                                                const float* __restrict__ a,
                                                const float* __restrict__ cc,
                                                unsigned short* __restrict__ outh) {
    const int total8 = NN * C / 8;
    for (int t = blockIdx.x * 256 + threadIdx.x; t < total8; t += gridDim.x * 256) {
        int ch = (t * 8) & 127;
        uint4 u = *reinterpret_cast<const uint4*>(in + (size_t)t * 8);
        float4 a4 = *reinterpret_cast<const float4*>(&a[ch]);
        float4 a4b = *reinterpret_cast<const float4*>(&a[ch + 4]);
        float4 c4 = *reinterpret_cast<const float4*>(&cc[ch]);
        float4 c4b = *reinterpret_cast<const float4*>(&cc[ch + 4]);
        float e0 = fmaxf(fmaf(__uint_as_float(u.x << 16),        a4.x,  c4.x), 0.f);
        float e1 = fmaxf(fmaf(__uint_as_float(u.x & 0xffff0000u), a4.y,  c4.y), 0.f);
        float e2 = fmaxf(fmaf(__uint_as_float(u.y << 16),        a4.z,  c4.z), 0.f);
        float e3 = fmaxf(fmaf(__uint_as_float(u.y & 0xffff0000u), a4.w,  c4.w), 0.f);
        float e4 = fmaxf(fmaf(__uint_as_float(u.z << 16),        a4b.x, c4b.x), 0.f);
        float e5 = fmaxf(fmaf(__uint_as_float(u.z & 0xffff0000u), a4b.y, c4b.y), 0.f);
        float e6 = fmaxf(fmaf(__uint_as_float(u.w << 16),        a4b.z, c4b.z), 0.f);
        float e7 = fmaxf(fmaf(__uint_as_float(u.w & 0xffff0000u), a4b.w, c4b.w), 0.f);
        uint4 pk;
        pk.x = pack_bf2(e0, e1); pk.y = pack_bf2(e2, e3);
        pk.z = pack_bf2(e4, e5); pk.w = pack_bf2(e6, e7);
        *reinterpret_cast<uint4*>(&outh[(size_t)t * 8]) = pk;
    }
}

// ---------------------------------------------------------------------------
// Fused attention with per-point compacted valid-tap lists.
// 16 points / 256-thread block; iterate only ~4.8 valid taps per point.
// ---------------------------------------------------------------------------
__global__ __launch_bounds__(256) void attn_fused16c(const unsigned short* __restrict__ vbf,
                                                     const float* __restrict__ qbuf,
                                                     const int* __restrict__ nA,
                                                     const int* __restrict__ nB,
                                                     const int* __restrict__ nC,
                                                     const float* __restrict__ cb0,
                                                     const float* __restrict__ cb1,
                                                     const float* __restrict__ cb2,
                                                     unsigned short* __restrict__ outm) {
    const int tid = threadIdx.x;
    const int base = blockIdx.x * 16;
    __shared__ int raw[16][41];
    __shared__ int sj[16][44];
    __shared__ short sk[16][44];
    __shared__ short sb[16][4];
    __shared__ float sattn[16][16][3];

    for (int t = tid; t < 656; t += 256) {
        int k = t >> 4, p = t & 15;
        int i = base + p;
        int j;
        if (k < 7)       j = nA[(size_t)k * NN + i];
        else if (k < 34) j = nB[(size_t)(k - 7) * NN + i];
        else             j = nC[(size_t)(k - 34) * NN + i];
        raw[p][k] = j;
    }
    __syncthreads();
    if (tid < 16) {
        int p = tid, n = 0;
#pragma unroll
        for (int k = 0; k < 7; ++k) { int j = raw[p][k]; if (j >= 0) { sj[p][n] = j; sk[p][n] = (short)k; ++n; } }
        int b0 = n;
#pragma unroll
        for (int k = 7; k < 34; ++k) { int j = raw[p][k]; if (j >= 0) { sj[p][n] = j; sk[p][n] = (short)(k - 7); ++n; } }
        int b1 = n;
#pragma unroll
        for (int k = 34; k < 41; ++k) { int j = raw[p][k]; if (j >= 0) { sj[p][n] = j; sk[p][n] = (short)(k - 34); ++n; } }
        sb[p][0] = (short)b0; sb[p][1] = (short)b1; sb[p][2] = (short)n;
    }
    __syncthreads();
    {   // scores + softmax: 16p x 16v
        int p = tid >> 4, v = tid & 15;
        int b0 = sb[p][0], b1 = sb[p][1], b2 = sb[p][2];
        float qi = qbuf[(size_t)(base + p) * VEC + v];
        float a0 = 0.f, a1 = 0.f, a2 = 0.f;
        for (int s = 0; s < b0; ++s) a0 += qbuf[(size_t)sj[p][s] * VEC + v];
        for (int s = b0; s < b1; ++s) a1 += qbuf[(size_t)sj[p][s] * VEC + v];
        for (int s = b1; s < b2; ++s) a2 += qbuf[(size_t)sj[p][s] * VEC + v];
        float s0 = qi * a0 / (float)(b0 > 0 ? b0 : 1);
        float s1 = qi * a1 / (float)(b1 - b0 > 0 ? b1 - b0 : 1);
        float s2 = qi * a2 / (float)(b2 - b1 > 0 ? b2 - b1 : 1);
        float mx = fmaxf(s0, fmaxf(s1, s2));
        float e0 = __expf(s0 - mx), e1 = __expf(s1 - mx), e2 = __expf(s2 - mx);
        float inv = 1.f / (e0 + e1 + e2);
        sattn[p][v][0] = e0 * inv; sattn[p][v][1] = e1 * inv; sattn[p][v][2] = e2 * inv;
    }
    __syncthreads();
    {   // channelwise mix: 16p x 16 lanes x 8 channels
        int p = tid >> 4, g = tid & 15, c0 = g * 8;
        int b0 = sb[p][0], b1 = sb[p][1], b2 = sb[p][2];
        float A0[8], A1[8], A2[8];
#pragma unroll
        for (int c = 0; c < 8; ++c) { A0[c] = 0.f; A1[c] = 0.f; A2[c] = 0.f; }
        for (int s = 0; s < b0; ++s) {
            int j = sj[p][s], k = sk[p][s];
            uint4 u = *reinterpret_cast<const uint4*>(vbf + (size_t)j * C + c0);
            float4 ca = *reinterpret_cast<const float4*>(&cb0[k * C + c0]);
            float4 cb = *reinterpret_cast<const float4*>(&cb0[k * C + c0 + 4]);
            A0[0] = fmaf(ca.x, __uint_as_float(u.x << 16), A0[0]);
            A0[1] = fmaf(ca.y, __uint_as_float(u.x & 0xffff0000u), A0[1]);
            A0[2] = fmaf(ca.z, __uint_as_float(u.y << 16), A0[2]);
            A0[3] = fmaf(ca.w, __uint_as_float(u.y & 0xffff0000u), A0[3]);
            A0[4] = fmaf(cb.x, __uint_as_float(u.z << 16), A0[4]);
            A0[5] = fmaf(cb.y, __uint_as_float(u.z & 0xffff0000u), A0[5]);
            A0[6] = fmaf(cb.z, __uint_as_float(u.w << 16), A0[6]);
            A0[7] = fmaf(cb.w, __uint_as_float(u.w & 0xffff0000u), A0[7]);
        }
        for (int s = b0; s < b1; ++s) {
            int j = sj[p][s], k = sk[p][s];
            uint4 u = *reinterpret_cast<const uint4*>(vbf + (size_t)j * C + c0);
            float4 ca = *reinterpret_cast<const float4*>(&cb1[k * C + c0]);
            float4 cb = *reinterpret_cast<const float4*>(&cb1[k * C + c0 + 4]);
            A1[0] = fmaf(ca.x, __uint_as_float(u.x << 16), A1[0]);
            A1[1] = fmaf(ca.y, __uint_as_float(u.x & 0xffff0000u), A1[1]);
            A1[2] = fmaf(ca.z, __uint_as_float(u.y << 16), A1[2]);
            A1[3] = fmaf(ca.w, __uint_as_float(u.y & 0xffff0000u), A1[3]);
            A1[4] = fmaf(cb.x, __uint_as_float(u.z << 16), A1[4]);
            A1[5] = fmaf(cb.y, __uint_as_float(u.z & 0xffff0000u), A1[5]);
            A1[6] = fmaf(cb.z, __uint_as_float(u.w << 16), A1[6]);
            A1[7] = fmaf(cb.w, __uint_as_float(u.w & 0xffff0000u), A1[7]);
        }
        for (int s = b1; s < b2; ++s) {
            int j = sj[p][s], k = sk[p][s];
            uint4 u = *reinterpret_cast<const uint4*>(vbf + (size_t)j * C + c0);
            float4 ca = *reinterpret_cast<const float4*>(&cb2[k * C + c0]);
            float4 cb = *reinterpret_cast<const float4*>(&cb2[k * C + c0 + 4]);
            A2[0] = fmaf(ca.x, __uint_as_float(u.x << 16), A2[0]);
            A2[1] = fmaf(ca.y, __uint_as_float(u.x & 0xffff0000u), A2[1]);
            A2[2] = fmaf(ca.z, __uint_as_float(u.y << 16), A2[2]);
            A2[3] = fmaf(ca.w, __uint_as_float(u.y & 0xffff0000u), A2[3]);
            A2[4] = fmaf(cb.x, __uint_as_float(u.z << 16), A2[4]);
            A2[5] = fmaf(cb.y, __uint_as_float(u.z & 0xffff0000u), A2[5]);
            A2[6] = fmaf(cb.z, __uint_as_float(u.w << 16), A2[6]);
            A2[7] = fmaf(cb.w, __uint_as_float(u.w & 0xffff0000u), A2[7]);
        }
        float w0 = sattn[p][g][0], w1 = sattn[p][g][1], w2 = sattn[p][g][2];
        float o[8];
#pragma unroll
        for (int c = 0; c < 8; ++c) o[c] = w0 * A0[c] + w1 * A1[c] + w2 * A2[c];
        uint4 pk;
        pk.x = pack_bf2(o[0], o[1]); pk.y = pack_bf2(o[2], o[3]);
        pk.z = pack_bf2(o[4], o[5]); pk.w = pack_bf2(o[6], o[7]);
        *reinterpret_cast<uint4*>(&outm[(size_t)(base + p) * C + c0]) = pk;
    }
}

// out = relu(bf16buf*a + c) + x   (fp32 out)
__global__ __launch_bounds__(256) void final_bn_res_h(const unsigned short* __restrict__ buf,
                                                      const float* __restrict__ a,
                                                      const float* __restrict__ cc,
                                                      const float* __restrict__ x,
                                                      float* __restrict__ out) {
    const int total8 = NN * C / 8;
    for (int t = blockIdx.x * 256 + threadIdx.x; t < total8; t += gridDim.x * 256) {
        int ch = (t * 8) & 127;
        uint4 u = *reinterpret_cast<const uint4*>(buf + (size_t)t * 8);
        float4 xa = *reinterpret_cast<const float4*>(x + (size_t)t * 8);
        float4 xb = *reinterpret_cast<const float4*>(x + (size_t)t * 8 + 4);
        float4 a4 = *reinterpret_cast<const float4*>(&a[ch]);
        float4 a4b = *reinterpret_cast<const float4*>(&a[ch + 4]);
        float4 c4 = *reinterpret_cast<const float4*>(&cc[ch]);
        float4 c4b = *reinterpret_cast<const float4*>(&cc[ch + 4]);
        float4 o0, o1;
        o0.x = fmaxf(fmaf(__uint_as_float(u.x << 16),        a4.x,  c4.x), 0.f) + xa.x;
        o0.y = fmaxf(fmaf(__uint_as_float(u.x & 0xffff0000u), a4.y,  c4.y), 0.f) + xa.y;
        o0.z = fmaxf(fmaf(__uint_as_float(u.y << 16),        a4.z,  c4.z), 0.f) + xa.z;
        o0.w = fmaxf(fmaf(__uint_as_float(u.y & 0xffff0000u), a4.w,  c4.w), 0.f) + xa.w;
        o1.x = fmaxf(fmaf(__uint_as_float(u.z << 16),        a4b.x, c4b.x), 0.f) + xb.x;
        o1.y = fmaxf(fmaf(__uint_as_float(u.z & 0xffff0000u), a4b.y, c4b.y), 0.f) + xb.y;
        o1.z = fmaxf(fmaf(__uint_as_float(u.w << 16),        a4b.z, c4b.z), 0.f) + xb.z;
        o1.w = fmaxf(fmaf(__uint_as_float(u.w & 0xffff0000u), a4b.w, c4b.w), 0.f) + xb.w;
        *reinterpret_cast<float4*>(out + (size_t)t * 8) = o0;
        *reinterpret_cast<float4*>(out + (size_t)t * 8 + 4) = o1;
    }
}

extern "C" void kernel_launch(void* const* d_in, const int* in_sizes, int n_in,
                              void* d_out, int out_size, void* d_ws, size_t ws_size,
                              hipStream_t stream) {
    (void)in_sizes; (void)n_in; (void)out_size; (void)ws_size;
    const float* x    = (const float*)d_in[0];
    const float* v1_w = (const float*)d_in[1];
    const float* v1_g = (const float*)d_in[2];
    const float* v1_b = (const float*)d_in[3];
    const float* v2_w = (const float*)d_in[4];
    const float* v2_g = (const float*)d_in[5];
    const float* v2_b = (const float*)d_in[6];
    const float* q_w  = (const float*)d_in[7];
    const float* q_g  = (const float*)d_in[8];
    const float* q_b  = (const float*)d_in[9];
    const float* cb0  = (const float*)d_in[10];
    const float* cb1  = (const float*)d_in[11];
    const float* cb2  = (const float*)d_in[12];
    const float* out_w = (const float*)d_in[13];
    const float* out_g = (const float*)d_in[14];
    const float* out_b = (const float*)d_in[15];
    const int* nbrA = (const int*)d_in[16];   // cross2, K=7
    const int* nbrB = (const int*)d_in[17];   // cube,  K=27
    const int* nbrC = (const int*)d_in[18];   // cross3, K=7
    float* out = (float*)d_out;

    float* w = (float*)d_ws;
    // region0: bufAh (bf16 conv1-out; later bf16 attn-out)
    unsigned short* bufAh = (unsigned short*)w;                // NN*C ushorts = 6.4M floats
    float* r1 = w + (size_t)NN * C / 2;
    // region1 (conv-stage), later aliased by {bufBh, bufQ, vbf}:
    unsigned short* g = (unsigned short*)r1;                   // GCAP*C ushorts = 15.36M floats
    int* slotmap = (int*)(r1 + 15360000);                      // 27*NN ints
    int* pairs   = (int*)(r1 + 15360000 + 2700000);            // 27*NN ints
    unsigned short* bufBh = (unsigned short*)r1;               // NN*C ushorts (6.4M floats)
    float* bufQ = r1 + 6400000;                                // NN*VEC floats (1.6M)
    unsigned short* vbf = (unsigned short*)(r1 + 6400000 + 1600000); // NN*C ushorts (6.4M floats)
    size_t o = (size_t)NN * C / 2 + 20760000;                  // end of region1
    float* psb  = w + o; o += (size_t)6250 * C;
    float* pqb  = w + o; o += (size_t)6250 * C;
    float* ps2  = w + o; o += 64 * C;
    float* pq2  = w + o; o += 64 * C;
    float* ps16 = w + o; o += 128 * VEC;
    float* pq16 = w + o; o += 128 * VEC;
    float* a1 = w + o; o += C;  float* c1 = w + o; o += C;
    float* a2 = w + o; o += C;  float* c2 = w + o; o += C;
    float* ao = w + o; o += C;  float* co = w + o; o += C;
    float* aq = w + o; o += VEC; float* cq = w + o; o += VEC;
    unsigned short* v1f = (unsigned short*)(w + o); o += (27 * 16384) / 2;
    unsigned short* v2f = (unsigned short*)(w + o); o += 16384 / 2;
    unsigned short* outf = (unsigned short*)(w + o); o += 16384 / 2;
    int* hdr = (int*)(w + o); o += 128;
    unsigned* maskbuf = (unsigned*)(w + o); o += NN;

    const int total4q = NN * VEC / 4;

    hipMemsetAsync(hdr, 0, (size_t)(128 + NN) * sizeof(int), stream);
    prep<<<1856, 256, 0, stream>>>(v1_w, v2_w, out_w, v1f, v2f, outf);

    // conv1 (cube-27): compaction + dense GEMM + scatter-sum (bf16 out)
    compactA<<<27 * 49, 256, 0, stream>>>(nbrB, hdr, slotmap, pairs, maskbuf);
    prefixA2<<<1, 64, 0, stream>>>(hdr);
    convB<<<2048, 256, 0, stream>>>(x, pairs, hdr, (const bfx8*)v1f, g);
    convC<<<NN / 16, 256, 0, stream>>>(g, slotmap, hdr, maskbuf, bufAh, psb, pqb);
    stats_mid128<<<64, 256, 0, stream>>>(psb, pqb, 6250, ps2, pq2);
    stats_final<<<1, 128, 0, stream>>>(ps2, pq2, 64, C, v1_g, v1_b, a1, c1);

    // v2 1x1 conv (fused input BN+ReLU) -> bufBh (g/slotmap/pairs dead now)
    mm_bn_h<<<NN / 16, 256, 0, stream>>>(bufAh, a1, c1, 1, (const bfx8*)v2f, bufBh, psb, pqb);
    stats_mid128<<<64, 256, 0, stream>>>(psb, pqb, 6250, ps2, pq2);
    stats_final<<<1, 128, 0, stream>>>(ps2, pq2, 64, C, v2_g, v2_b, a2, c2);

    // v = relu(bn(bufBh)) as bf16 -> vbf
    bnrelu_h<<<2048, 256, 0, stream>>>(bufBh, a2, c2, vbf);

    // query branch
    qmm<<<NN / 16, 256, 0, stream>>>(x, q_w, bufQ);
    stats_partial16<<<128, 256, 0, stream>>>(bufQ, ps16, pq16);
    stats_final<<<1, 64, 0, stream>>>(ps16, pq16, 128, VEC, q_g, q_b, aq, cq);
    bn_relu_ip<<<1024, 256, 0, stream>>>(bufQ, aq, cq, total4q, 15);

    // fused expert convs + attention mix (compacted taps) -> bufAh (bf16)
    attn_fused16c<<<NN / 16, 256, 0, stream>>>(vbf, bufQ, nbrA, nbrB, nbrC, cb0, cb1, cb2, bufAh);

    // output 1x1 conv -> bufBh (bf16), fused stats; final residual
    mm_bn_h<<<NN / 16, 256, 0, stream>>>(bufAh, nullptr, nullptr, 0, (const bfx8*)outf, bufBh, psb, pqb);
    stats_mid128<<<64, 256, 0, stream>>>(psb, pqb, 6250, ps2, pq2);
    stats_final<<<1, 128, 0, stream>>>(ps2, pq2, 64, C, out_g, out_b, ao, co);
    final_bn_res_h<<<2048, 256, 0, stream>>>(bufBh, ao, co, x, out);
}